// Round 1
// baseline (5012.793 us; speedup 1.0000x reference)
//
#include <hip/hip_runtime.h>
#include <hip/hip_bf16.h>

#define NN 50000
#define EE 500000
#define GG 64
#define HIDD 128
#define HEADS 8
#define DHH 16

// ---------------- degree / norm ----------------
__global__ void deg_kernel(const int* __restrict__ src, const int* __restrict__ dst,
                           float* __restrict__ degS, float* __restrict__ degD) {
  int i = blockIdx.x * blockDim.x + threadIdx.x;
  int stride = gridDim.x * blockDim.x;
  for (; i < EE; i += stride) {
    atomicAdd(&degS[src[i]], 1.0f);
    atomicAdd(&degD[dst[i]], 1.0f);
  }
}

__global__ void norm_kernel(float* ns, float* nd) {
  int i = blockIdx.x * blockDim.x + threadIdx.x;
  if (i < NN) {
    ns[i] = 1.0f / sqrtf(fmaxf(ns[i], 1.0f));
    nd[i] = 1.0f / sqrtf(fmaxf(nd[i], 1.0f));
  }
}

// ---------------- GEMM [N,128] @ [128,128] ----------------
// out[r][c] = act( (A[r]*rowscale[r]) . W[:,c] + bias[c] )
__global__ __launch_bounds__(256) void gemm128(
    const float* __restrict__ A, const float* __restrict__ W,
    const float* __restrict__ bias, const float* __restrict__ rowscale,
    float* __restrict__ out, int relu)
{
  __shared__ float As[64][33];   // padded: bank-conflict-free row reads
  __shared__ float Ws[32][128];
  int tid = threadIdx.x;
  int r0 = blockIdx.x * 64;
  float acc[4][8];
#pragma unroll
  for (int r = 0; r < 4; ++r)
#pragma unroll
    for (int c = 0; c < 8; ++c) acc[r][c] = 0.f;
  int tr = tid >> 4, tc = tid & 15;
  for (int k0 = 0; k0 < 128; k0 += 32) {
    // W tile rows k0..k0+31, all 128 cols: contiguous 16KB
    const float4* Wg = (const float4*)(W + k0 * 128);
    float4* Wsv = (float4*)&Ws[0][0];
#pragma unroll
    for (int i = 0; i < 4; ++i) Wsv[tid + 256 * i] = Wg[tid + 256 * i];
    // A tile rows r0..r0+63, cols k0..k0+31
#pragma unroll
    for (int p = 0; p < 2; ++p) {
      int rr = p * 32 + (tid >> 3);
      int qq = tid & 7;
      int grow = r0 + rr;
      float4 v = make_float4(0.f, 0.f, 0.f, 0.f);
      if (grow < NN) {
        v = *(const float4*)(A + grow * 128 + k0 + qq * 4);
        if (rowscale) { float s = rowscale[grow]; v.x *= s; v.y *= s; v.z *= s; v.w *= s; }
      }
      As[rr][qq * 4 + 0] = v.x; As[rr][qq * 4 + 1] = v.y;
      As[rr][qq * 4 + 2] = v.z; As[rr][qq * 4 + 3] = v.w;
    }
    __syncthreads();
#pragma unroll
    for (int k = 0; k < 32; ++k) {
      float4 w0 = *(const float4*)&Ws[k][tc * 8];
      float4 w1 = *(const float4*)&Ws[k][tc * 8 + 4];
#pragma unroll
      for (int r = 0; r < 4; ++r) {
        float a = As[tr * 4 + r][k];
        acc[r][0] += a * w0.x; acc[r][1] += a * w0.y; acc[r][2] += a * w0.z; acc[r][3] += a * w0.w;
        acc[r][4] += a * w1.x; acc[r][5] += a * w1.y; acc[r][6] += a * w1.z; acc[r][7] += a * w1.w;
      }
    }
    __syncthreads();
  }
#pragma unroll
  for (int r = 0; r < 4; ++r) {
    int grow = r0 + tr * 4 + r;
    if (grow < NN) {
      float o[8];
#pragma unroll
      for (int c = 0; c < 8; ++c) {
        float v = acc[r][c];
        if (bias) v += bias[tc * 8 + c];
        if (relu) v = fmaxf(v, 0.f);
        o[c] = v;
      }
      *(float4*)(out + grow * 128 + tc * 8)     = make_float4(o[0], o[1], o[2], o[3]);
      *(float4*)(out + grow * 128 + tc * 8 + 4) = make_float4(o[4], o[5], o[6], o[7]);
    }
  }
}

// ---------------- GraphConv scatter ----------------
__global__ void scatter_add_kernel(const float* __restrict__ m,
                                   const int* __restrict__ src, const int* __restrict__ dst,
                                   float* __restrict__ agg)
{
  int idx = blockIdx.x * blockDim.x + threadIdx.x;  // E*32
  if (idx >= EE * 32) return;
  int e = idx >> 5;
  int q = (idx & 31) * 4;
  int s = src[e], d = dst[e];
  float4 v = *(const float4*)(m + s * 128 + q);
  float* o = agg + d * 128 + q;
  atomicAdd(o + 0, v.x); atomicAdd(o + 1, v.y);
  atomicAdd(o + 2, v.z); atomicAdd(o + 3, v.w);
}

__global__ void finalize_gc(const float* __restrict__ agg, const float* __restrict__ nd,
                            const float* __restrict__ bias, float* __restrict__ out)
{
  int idx = blockIdx.x * blockDim.x + threadIdx.x;
  if (idx >= NN * HIDD) return;
  int r = idx >> 7, c = idx & 127;
  out[idx] = fmaxf(agg[idx] * nd[r] + bias[c], 0.f);
}

// ---------------- GATv2 edge kernels ----------------
__device__ inline unsigned encf(float f) {
  unsigned u = __float_as_uint(f);
  return (u & 0x80000000u) ? ~u : (u | 0x80000000u);
}
__device__ inline float decf(unsigned u) {
  unsigned b = (u & 0x80000000u) ? (u ^ 0x80000000u) : ~u;
  return __uint_as_float(b);
}

__global__ void edge_logit_kernel(const float* __restrict__ fs, const float* __restrict__ fd,
                                  const float* __restrict__ attn,  // [8][16]
                                  const int* __restrict__ src, const int* __restrict__ dst,
                                  float* __restrict__ logit, unsigned* __restrict__ nodemax)
{
  __shared__ float a_s[HEADS * DHH];
  if (threadIdx.x < HEADS * DHH) a_s[threadIdx.x] = attn[threadIdx.x];
  __syncthreads();
  int idx = blockIdx.x * blockDim.x + threadIdx.x;
  if (idx >= EE * HEADS) return;
  int e = idx >> 3, h = idx & 7;
  int s = src[e], d = dst[e];
  const float* ps = fs + s * 128 + h * 16;
  const float* pd = fd + d * 128 + h * 16;
  float acc = 0.f;
#pragma unroll
  for (int q = 0; q < 4; ++q) {
    float4 vs = *(const float4*)(ps + q * 4);
    float4 vd = *(const float4*)(pd + q * 4);
    float x;
    x = vs.x + vd.x; acc += a_s[h * 16 + q * 4 + 0] * (x > 0.f ? x : 0.2f * x);
    x = vs.y + vd.y; acc += a_s[h * 16 + q * 4 + 1] * (x > 0.f ? x : 0.2f * x);
    x = vs.z + vd.z; acc += a_s[h * 16 + q * 4 + 2] * (x > 0.f ? x : 0.2f * x);
    x = vs.w + vd.w; acc += a_s[h * 16 + q * 4 + 3] * (x > 0.f ? x : 0.2f * x);
  }
  logit[idx] = acc;
  atomicMax(&nodemax[d * 8 + h], encf(acc));
}

__global__ void edge_exp_kernel(const int* __restrict__ dst, float* __restrict__ logit,
                                const unsigned* __restrict__ nodemax, float* __restrict__ nodesum)
{
  int idx = blockIdx.x * blockDim.x + threadIdx.x;
  if (idx >= EE * HEADS) return;
  int e = idx >> 3, h = idx & 7;
  int d = dst[e];
  float m = decf(nodemax[d * 8 + h]);
  float p = expf(logit[idx] - m);
  logit[idx] = p;
  atomicAdd(&nodesum[d * 8 + h], p);
}

__global__ void edge_agg_kernel(const float* __restrict__ fs, const float* __restrict__ p,
                                const float* __restrict__ nodesum,
                                const int* __restrict__ src, const int* __restrict__ dst,
                                float* __restrict__ agg)
{
  int idx = blockIdx.x * blockDim.x + threadIdx.x;  // E*32
  if (idx >= EE * 32) return;
  int e = idx >> 5;
  int sub = idx & 31;
  int h = sub >> 2;
  int s = src[e], d = dst[e];
  float alpha = p[e * 8 + h] / nodesum[d * 8 + h];
  float4 v = *(const float4*)(fs + s * 128 + sub * 4);
  float* o = agg + d * 128 + sub * 4;
  atomicAdd(o + 0, alpha * v.x); atomicAdd(o + 1, alpha * v.y);
  atomicAdd(o + 2, alpha * v.z); atomicAdd(o + 3, alpha * v.w);
}

__global__ void finalize_gat(const float* __restrict__ agg, float* __restrict__ h)
{
  int idx = blockIdx.x * blockDim.x + threadIdx.x;
  if (idx >= NN * HIDD) return;
  h[idx] = fmaxf(agg[idx] + h[idx], 0.f);
}

// ---------------- pooling + MLP ----------------
__global__ void pool_kernel(const float* __restrict__ h, const int* __restrict__ n2g,
                            unsigned* __restrict__ hg)
{
  int idx = blockIdx.x * blockDim.x + threadIdx.x;
  if (idx >= NN * HIDD) return;
  int r = idx >> 7, c = idx & 127;
  int g = n2g[r];
  // h >= 0 after relu: uint compare == float compare; hg zero-initialized
  atomicMax(&hg[g * 128 + c], __float_as_uint(h[idx]));
}

__global__ __launch_bounds__(128) void mlp_kernel(
    const float* __restrict__ hg,
    const float* __restrict__ Wc1, const float* __restrict__ bc1,
    const float* __restrict__ Wc2, const float* __restrict__ bc2,
    const float* __restrict__ Wc3, const float* __restrict__ bc3,
    float* __restrict__ out)
{
  __shared__ float x[128], z1[128], z2[64];
  int g = blockIdx.x, t = threadIdx.x;
  x[t] = hg[g * 128 + t];
  __syncthreads();
  float acc = bc1[t];
  for (int k = 0; k < 128; ++k) acc += x[k] * Wc1[k * 128 + t];
  z1[t] = fmaxf(acc, 0.f);
  __syncthreads();
  if (t < 64) {
    float a2 = bc2[t];
    for (int k = 0; k < 128; ++k) a2 += z1[k] * Wc2[k * 64 + t];
    z2[t] = fmaxf(a2, 0.f);
  }
  __syncthreads();
#pragma unroll
  for (int p = 0; p < 2; ++p) {
    int c = t + p * 128;
    float a3 = bc3[c];
    for (int k = 0; k < 64; ++k) a3 += z2[k] * Wc3[k * 256 + c];
    out[g * 256 + c] = a3;
  }
}

// ---------------- launch ----------------
extern "C" void kernel_launch(void* const* d_in, const int* in_sizes, int n_in,
                              void* d_out, int out_size, void* d_ws, size_t ws_size,
                              hipStream_t stream)
{
  const float* feature = (const float*)d_in[0];
  const float* W_gc1 = (const float*)d_in[1];
  const float* b_gc1 = (const float*)d_in[2];
  const float* W_gc2 = (const float*)d_in[3];
  const float* b_gc2 = (const float*)d_in[4];
  const float* W_src = (const float*)d_in[5];
  const float* b_src = (const float*)d_in[6];
  const float* W_dst = (const float*)d_in[7];
  const float* b_dst = (const float*)d_in[8];
  const float* attn  = (const float*)d_in[9];
  const float* Wc1 = (const float*)d_in[10];
  const float* bc1 = (const float*)d_in[11];
  const float* Wc2 = (const float*)d_in[12];
  const float* bc2 = (const float*)d_in[13];
  const float* Wc3 = (const float*)d_in[14];
  const float* bc3 = (const float*)d_in[15];
  const int* src = (const int*)d_in[16];
  const int* dst = (const int*)d_in[17];
  const int* n2g = (const int*)d_in[18];

  float* ws = (float*)d_ws;
  float* ns = ws;                ws += NN;
  float* nd = ws;                ws += NN;
  float* h0 = ws;                ws += NN * HIDD;
  float* h1 = ws;                ws += NN * HIDD;
  float* fs = ws;                ws += NN * HIDD;
  float* fd = ws;                ws += NN * HIDD;
  float* logit = ws;             ws += EE * HEADS;
  float* nodesum = ws;           ws += NN * HEADS;
  unsigned* nodemax = (unsigned*)ws; ws += NN * HEADS;
  float* hg = ws;                ws += GG * HIDD;

  // degrees & norms (ns/nd double as degree accumulators)
  hipMemsetAsync(ns, 0, 2 * NN * sizeof(float), stream);
  deg_kernel<<<2048, 256, 0, stream>>>(src, dst, ns, nd);
  norm_kernel<<<(NN + 255) / 256, 256, 0, stream>>>(ns, nd);

  const int gemm_grid = (NN + 63) / 64;
  const int ew_grid = NN * HIDD / 256;       // 25000, exact
  const int e32_grid = EE * 32 / 256;        // 62500, exact
  const int eh_grid = EE * HEADS / 256;      // 15625, exact

  // GraphConv 1 (fs doubles as m-scratch)
  gemm128<<<gemm_grid, 256, 0, stream>>>(feature, W_gc1, nullptr, ns, fs, 0);
  hipMemsetAsync(h1, 0, NN * HIDD * sizeof(float), stream);
  scatter_add_kernel<<<e32_grid, 256, 0, stream>>>(fs, src, dst, h1);
  finalize_gc<<<ew_grid, 256, 0, stream>>>(h1, nd, b_gc1, h0);
  // GraphConv 2
  gemm128<<<gemm_grid, 256, 0, stream>>>(h0, W_gc2, nullptr, ns, fs, 0);
  hipMemsetAsync(h1, 0, NN * HIDD * sizeof(float), stream);
  scatter_add_kernel<<<e32_grid, 256, 0, stream>>>(fs, src, dst, h1);
  finalize_gc<<<ew_grid, 256, 0, stream>>>(h1, nd, b_gc2, h0);

  // GATv2 x3
  for (int i = 0; i < 3; ++i) {
    gemm128<<<gemm_grid, 256, 0, stream>>>(h0, W_src + i * HIDD * HIDD, b_src + i * HIDD, nullptr, fs, 0);
    gemm128<<<gemm_grid, 256, 0, stream>>>(h0, W_dst + i * HIDD * HIDD, b_dst + i * HIDD, nullptr, fd, 0);
    hipMemsetAsync(nodesum, 0, NN * HEADS * sizeof(float), stream);
    hipMemsetAsync(nodemax, 0, NN * HEADS * sizeof(unsigned), stream);
    edge_logit_kernel<<<eh_grid, 256, 0, stream>>>(fs, fd, attn + i * HEADS * DHH, src, dst, logit, nodemax);
    edge_exp_kernel<<<eh_grid, 256, 0, stream>>>(dst, logit, nodemax, nodesum);
    hipMemsetAsync(h1, 0, NN * HIDD * sizeof(float), stream);
    edge_agg_kernel<<<e32_grid, 256, 0, stream>>>(fs, logit, nodesum, src, dst, h1);
    finalize_gat<<<ew_grid, 256, 0, stream>>>(h1, h0);
  }

  // pooling + MLP
  hipMemsetAsync(hg, 0, GG * HIDD * sizeof(float), stream);
  pool_kernel<<<ew_grid, 256, 0, stream>>>(h0, n2g, (unsigned*)hg);
  mlp_kernel<<<GG, 128, 0, stream>>>(hg, Wc1, bc1, Wc2, bc2, Wc3, bc3, (float*)d_out);
}

// Round 2
// 1267.310 us; speedup vs baseline: 3.9555x; 3.9555x over previous
//
#include <hip/hip_runtime.h>
#include <hip/hip_bf16.h>

#define NN 50000
#define EE 500000
#define GG 64
#define HIDD 128
#define HEADS 8
#define DHH 16

// ---------------- degree ----------------
__global__ void deg_kernel(const int* __restrict__ src, const int* __restrict__ dst,
                           int* __restrict__ outdeg, int* __restrict__ indeg) {
  int i = blockIdx.x * blockDim.x + threadIdx.x;
  int stride = gridDim.x * blockDim.x;
  for (; i < EE; i += stride) {
    atomicAdd(&outdeg[src[i]], 1);
    atomicAdd(&indeg[dst[i]], 1);
  }
}

__global__ void norm_kernel(const int* __restrict__ outdeg, float* __restrict__ ns) {
  int i = blockIdx.x * blockDim.x + threadIdx.x;
  if (i < NN) ns[i] = rsqrtf((float)max(outdeg[i], 1));
}

// ---------------- CSR build: exclusive scan + binning ----------------
__global__ __launch_bounds__(256) void scan_kernel(const int* __restrict__ deg,
                                                   int* __restrict__ rowoff,
                                                   int* __restrict__ cursor) {
  __shared__ int buf[256];
  __shared__ int carry_s;
  int t = threadIdx.x;
  if (t == 0) carry_s = 0;
  __syncthreads();
  for (int base = 0; base < NN; base += 256) {
    int idx = base + t;
    int v = (idx < NN) ? deg[idx] : 0;
    buf[t] = v;
    __syncthreads();
#pragma unroll
    for (int off = 1; off < 256; off <<= 1) {
      int tmp = (t >= off) ? buf[t - off] : 0;
      __syncthreads();
      buf[t] += tmp;
      __syncthreads();
    }
    int excl = buf[t] - v + carry_s;
    if (idx < NN) { rowoff[idx] = excl; cursor[idx] = excl; }
    __syncthreads();
    if (t == 255) carry_s += buf[255];
    __syncthreads();
  }
}

__global__ void bin_kernel(const int* __restrict__ src, const int* __restrict__ dst,
                           int* __restrict__ cursor, int* __restrict__ csr_src) {
  int i = blockIdx.x * blockDim.x + threadIdx.x;
  int stride = gridDim.x * blockDim.x;
  for (; i < EE; i += stride) {
    int pos = atomicAdd(&cursor[dst[i]], 1);
    csr_src[pos] = src[i];
  }
}

// ---------------- GEMM [N,128] @ [128,128] ----------------
__global__ __launch_bounds__(256) void gemm128(
    const float* __restrict__ A, const float* __restrict__ W,
    const float* __restrict__ bias, const float* __restrict__ rowscale,
    float* __restrict__ out, int relu)
{
  __shared__ float As[64][33];
  __shared__ float Ws[32][128];
  int tid = threadIdx.x;
  int r0 = blockIdx.x * 64;
  float acc[4][8];
#pragma unroll
  for (int r = 0; r < 4; ++r)
#pragma unroll
    for (int c = 0; c < 8; ++c) acc[r][c] = 0.f;
  int tr = tid >> 4, tc = tid & 15;
  for (int k0 = 0; k0 < 128; k0 += 32) {
    const float4* Wg = (const float4*)(W + k0 * 128);
    float4* Wsv = (float4*)&Ws[0][0];
#pragma unroll
    for (int i = 0; i < 4; ++i) Wsv[tid + 256 * i] = Wg[tid + 256 * i];
#pragma unroll
    for (int p = 0; p < 2; ++p) {
      int rr = p * 32 + (tid >> 3);
      int qq = tid & 7;
      int grow = r0 + rr;
      float4 v = make_float4(0.f, 0.f, 0.f, 0.f);
      if (grow < NN) {
        v = *(const float4*)(A + grow * 128 + k0 + qq * 4);
        if (rowscale) { float s = rowscale[grow]; v.x *= s; v.y *= s; v.z *= s; v.w *= s; }
      }
      As[rr][qq * 4 + 0] = v.x; As[rr][qq * 4 + 1] = v.y;
      As[rr][qq * 4 + 2] = v.z; As[rr][qq * 4 + 3] = v.w;
    }
    __syncthreads();
#pragma unroll
    for (int k = 0; k < 32; ++k) {
      float4 w0 = *(const float4*)&Ws[k][tc * 8];
      float4 w1 = *(const float4*)&Ws[k][tc * 8 + 4];
#pragma unroll
      for (int r = 0; r < 4; ++r) {
        float a = As[tr * 4 + r][k];
        acc[r][0] += a * w0.x; acc[r][1] += a * w0.y; acc[r][2] += a * w0.z; acc[r][3] += a * w0.w;
        acc[r][4] += a * w1.x; acc[r][5] += a * w1.y; acc[r][6] += a * w1.z; acc[r][7] += a * w1.w;
      }
    }
    __syncthreads();
  }
#pragma unroll
  for (int r = 0; r < 4; ++r) {
    int grow = r0 + tr * 4 + r;
    if (grow < NN) {
      float o[8];
#pragma unroll
      for (int c = 0; c < 8; ++c) {
        float v = acc[r][c];
        if (bias) v += bias[tc * 8 + c];
        if (relu) v = fmaxf(v, 0.f);
        o[c] = v;
      }
      *(float4*)(out + grow * 128 + tc * 8)     = make_float4(o[0], o[1], o[2], o[3]);
      *(float4*)(out + grow * 128 + tc * 8 + 4) = make_float4(o[4], o[5], o[6], o[7]);
    }
  }
}

// ---------------- GraphConv aggregation: CSR gather, fused norm+bias+relu ----------------
__global__ __launch_bounds__(128) void gc_agg_kernel(
    const float* __restrict__ m, const int* __restrict__ rowoff,
    const int* __restrict__ indeg, const int* __restrict__ csr_src,
    const float* __restrict__ bias, float* __restrict__ out)
{
  int d = blockIdx.x;
  int c = threadIdx.x;
  int ro = rowoff[d];
  int dg = indeg[d];
  float acc = 0.f;
  for (int j = 0; j < dg; ++j) {
    int s = csr_src[ro + j];
    acc += m[s * 128 + c];
  }
  float ndv = rsqrtf((float)max(dg, 1));
  out[d * 128 + c] = fmaxf(acc * ndv + bias[c], 0.f);
}

// ---------------- Fused GATv2 per-node kernel ----------------
// pass1: gather fs[src], logit via 16-lane head reduce, store logit (CSR order), track max
// pass2: exp, accumulate sum & weighted fs; write relu(acc/s + h) in place
__global__ __launch_bounds__(128) void gat_node_kernel(
    const float* __restrict__ fs, const float* __restrict__ fd,
    const float* __restrict__ attn,  // 128 floats: a[h*16+dh]
    const int* __restrict__ rowoff, const int* __restrict__ indeg,
    const int* __restrict__ csr_src,
    float* __restrict__ logit,       // [E][8] in CSR position order
    float* __restrict__ h)           // in/out [N][128]
{
  int d = blockIdx.x;
  int c = threadIdx.x;
  int hh = c >> 4;
  int ro = rowoff[d];
  int dg = indeg[d];
  float fd_c = fd[d * 128 + c];
  float a_c = attn[c];
  float m = -INFINITY;
  for (int j = 0; j < dg; ++j) {
    int s = csr_src[ro + j];
    float x = fs[s * 128 + c] + fd_c;
    x = x > 0.f ? x : 0.2f * x;
    float y = a_c * x;
    y += __shfl_xor(y, 1);
    y += __shfl_xor(y, 2);
    y += __shfl_xor(y, 4);
    y += __shfl_xor(y, 8);
    if ((c & 15) == 0) logit[(ro + j) * 8 + hh] = y;
    m = fmaxf(m, y);
  }
  float s_h = 0.f;
  float acc = 0.f;
  for (int j = 0; j < dg; ++j) {
    int s = csr_src[ro + j];
    float p = expf(logit[(ro + j) * 8 + hh] - m);
    s_h += p;
    acc += p * fs[s * 128 + c];
  }
  float o = (dg > 0) ? (acc / s_h) : 0.f;
  h[d * 128 + c] = fmaxf(o + h[d * 128 + c], 0.f);
}

// ---------------- pooling + MLP ----------------
__global__ void pool_kernel(const float* __restrict__ h, const int* __restrict__ n2g,
                            unsigned* __restrict__ hg)
{
  int idx = blockIdx.x * blockDim.x + threadIdx.x;
  if (idx >= NN * HIDD) return;
  int r = idx >> 7, c = idx & 127;
  int g = n2g[r];
  atomicMax(&hg[g * 128 + c], __float_as_uint(h[idx]));  // h >= 0 post-relu
}

__global__ __launch_bounds__(128) void mlp_kernel(
    const float* __restrict__ hg,
    const float* __restrict__ Wc1, const float* __restrict__ bc1,
    const float* __restrict__ Wc2, const float* __restrict__ bc2,
    const float* __restrict__ Wc3, const float* __restrict__ bc3,
    float* __restrict__ out)
{
  __shared__ float x[128], z1[128], z2[64];
  int g = blockIdx.x, t = threadIdx.x;
  x[t] = hg[g * 128 + t];
  __syncthreads();
  float acc = bc1[t];
  for (int k = 0; k < 128; ++k) acc += x[k] * Wc1[k * 128 + t];
  z1[t] = fmaxf(acc, 0.f);
  __syncthreads();
  if (t < 64) {
    float a2 = bc2[t];
    for (int k = 0; k < 128; ++k) a2 += z1[k] * Wc2[k * 64 + t];
    z2[t] = fmaxf(a2, 0.f);
  }
  __syncthreads();
#pragma unroll
  for (int p = 0; p < 2; ++p) {
    int c = t + p * 128;
    float a3 = bc3[c];
    for (int k = 0; k < 64; ++k) a3 += z2[k] * Wc3[k * 256 + c];
    out[g * 256 + c] = a3;
  }
}

// ---------------- launch ----------------
extern "C" void kernel_launch(void* const* d_in, const int* in_sizes, int n_in,
                              void* d_out, int out_size, void* d_ws, size_t ws_size,
                              hipStream_t stream)
{
  const float* feature = (const float*)d_in[0];
  const float* W_gc1 = (const float*)d_in[1];
  const float* b_gc1 = (const float*)d_in[2];
  const float* W_gc2 = (const float*)d_in[3];
  const float* b_gc2 = (const float*)d_in[4];
  const float* W_src = (const float*)d_in[5];
  const float* b_src = (const float*)d_in[6];
  const float* W_dst = (const float*)d_in[7];
  const float* b_dst = (const float*)d_in[8];
  const float* attn  = (const float*)d_in[9];
  const float* Wc1 = (const float*)d_in[10];
  const float* bc1 = (const float*)d_in[11];
  const float* Wc2 = (const float*)d_in[12];
  const float* bc2 = (const float*)d_in[13];
  const float* Wc3 = (const float*)d_in[14];
  const float* bc3 = (const float*)d_in[15];
  const int* src = (const int*)d_in[16];
  const int* dst = (const int*)d_in[17];
  const int* n2g = (const int*)d_in[18];

  char* base = (char*)d_ws;
  int* indeg  = (int*)base;            base += NN * sizeof(int);
  int* outdeg = (int*)base;            base += NN * sizeof(int);
  int* rowoff = (int*)base;            base += NN * sizeof(int);
  int* cursor = (int*)base;            base += NN * sizeof(int);
  int* csr_src = (int*)base;           base += EE * sizeof(int);
  float* ns = (float*)base;            base += NN * sizeof(float);
  float* h0 = (float*)base;            base += NN * HIDD * sizeof(float);
  float* fs = (float*)base;            base += NN * HIDD * sizeof(float);
  float* fd = (float*)base;            base += NN * HIDD * sizeof(float);
  float* logit = (float*)base;         base += (size_t)EE * HEADS * sizeof(float);
  float* hg = (float*)base;            base += GG * HIDD * sizeof(float);

  // degrees, norms, CSR
  hipMemsetAsync(indeg, 0, 2 * NN * sizeof(int), stream);
  deg_kernel<<<2048, 256, 0, stream>>>(src, dst, outdeg, indeg);
  norm_kernel<<<(NN + 255) / 256, 256, 0, stream>>>(outdeg, ns);
  scan_kernel<<<1, 256, 0, stream>>>(indeg, rowoff, cursor);
  bin_kernel<<<2048, 256, 0, stream>>>(src, dst, cursor, csr_src);

  const int gemm_grid = (NN + 63) / 64;
  const int ew_grid = NN * HIDD / 256;

  // GraphConv 1 (fs doubles as m-scratch)
  gemm128<<<gemm_grid, 256, 0, stream>>>(feature, W_gc1, nullptr, ns, fs, 0);
  gc_agg_kernel<<<NN, 128, 0, stream>>>(fs, rowoff, indeg, csr_src, b_gc1, h0);
  // GraphConv 2
  gemm128<<<gemm_grid, 256, 0, stream>>>(h0, W_gc2, nullptr, ns, fs, 0);
  gc_agg_kernel<<<NN, 128, 0, stream>>>(fs, rowoff, indeg, csr_src, b_gc2, h0);

  // GATv2 x3
  for (int i = 0; i < 3; ++i) {
    gemm128<<<gemm_grid, 256, 0, stream>>>(h0, W_src + i * HIDD * HIDD, b_src + i * HIDD, nullptr, fs, 0);
    gemm128<<<gemm_grid, 256, 0, stream>>>(h0, W_dst + i * HIDD * HIDD, b_dst + i * HIDD, nullptr, fd, 0);
    gat_node_kernel<<<NN, 128, 0, stream>>>(fs, fd, attn + i * HEADS * DHH,
                                            rowoff, indeg, csr_src, logit, h0);
  }

  // pooling + MLP
  hipMemsetAsync(hg, 0, GG * HIDD * sizeof(float), stream);
  pool_kernel<<<ew_grid, 256, 0, stream>>>(h0, n2g, (unsigned*)hg);
  mlp_kernel<<<GG, 128, 0, stream>>>(hg, Wc1, bc1, Wc2, bc2, Wc3, bc3, (float*)d_out);
}

// Round 3
// 937.721 us; speedup vs baseline: 5.3457x; 1.3515x over previous
//
#include <hip/hip_runtime.h>
#include <hip/hip_bf16.h>

#define NN 50000
#define EE 500000
#define GG 64
#define HIDD 128
#define HEADS 8
#define DHH 16
#define NBLK ((NN + 255) / 256)   // 196

// ---------------- degree ----------------
__global__ void deg_kernel(const int* __restrict__ src, const int* __restrict__ dst,
                           int* __restrict__ outdeg, int* __restrict__ indeg) {
  int i = blockIdx.x * blockDim.x + threadIdx.x;
  int stride = gridDim.x * blockDim.x;
  for (; i < EE; i += stride) {
    atomicAdd(&outdeg[src[i]], 1);
    atomicAdd(&indeg[dst[i]], 1);
  }
}

__global__ void norm_kernel(const int* __restrict__ outdeg, float* __restrict__ ns) {
  int i = blockIdx.x * blockDim.x + threadIdx.x;
  if (i < NN) ns[i] = rsqrtf((float)max(outdeg[i], 1));
}

// ---------------- hierarchical exclusive scan ----------------
__global__ __launch_bounds__(256) void scan1_kernel(const int* __restrict__ deg,
                                                    int* __restrict__ excl,
                                                    int* __restrict__ bsum) {
  __shared__ int buf[256];
  int t = threadIdx.x;
  int idx = blockIdx.x * 256 + t;
  int v = (idx < NN) ? deg[idx] : 0;
  buf[t] = v;
  __syncthreads();
#pragma unroll
  for (int off = 1; off < 256; off <<= 1) {
    int tmp = (t >= off) ? buf[t - off] : 0;
    __syncthreads();
    buf[t] += tmp;
    __syncthreads();
  }
  if (idx < NN) excl[idx] = buf[t] - v;
  if (t == 255) bsum[blockIdx.x] = buf[255];
}

__global__ __launch_bounds__(256) void scan2_kernel(int* __restrict__ bsum) {
  __shared__ int buf[256];
  int t = threadIdx.x;
  int v = (t < NBLK) ? bsum[t] : 0;
  buf[t] = v;
  __syncthreads();
#pragma unroll
  for (int off = 1; off < 256; off <<= 1) {
    int tmp = (t >= off) ? buf[t - off] : 0;
    __syncthreads();
    buf[t] += tmp;
    __syncthreads();
  }
  if (t < NBLK) bsum[t] = buf[t] - v;   // exclusive block offsets
}

__global__ __launch_bounds__(256) void scan3_kernel(int* __restrict__ excl,
                                                    const int* __restrict__ bsum,
                                                    int* __restrict__ cursor) {
  int idx = blockIdx.x * 256 + threadIdx.x;
  if (idx < NN) {
    int v = excl[idx] + bsum[blockIdx.x];
    excl[idx] = v;       // becomes rowoff
    cursor[idx] = v;
  }
}

__global__ void bin_kernel(const int* __restrict__ src, const int* __restrict__ dst,
                           int* __restrict__ cursor, int* __restrict__ csr_src) {
  int i = blockIdx.x * blockDim.x + threadIdx.x;
  int stride = gridDim.x * blockDim.x;
  for (; i < EE; i += stride) {
    int pos = atomicAdd(&cursor[dst[i]], 1);
    csr_src[pos] = src[i];
  }
}

// ---------------- GEMM [N,128] @ [128,128] ----------------
__global__ __launch_bounds__(256) void gemm128(
    const float* __restrict__ A, const float* __restrict__ W,
    const float* __restrict__ bias, const float* __restrict__ rowscale,
    float* __restrict__ out, int relu)
{
  __shared__ float As[64][33];
  __shared__ float Ws[32][128];
  int tid = threadIdx.x;
  int r0 = blockIdx.x * 64;
  float acc[4][8];
#pragma unroll
  for (int r = 0; r < 4; ++r)
#pragma unroll
    for (int c = 0; c < 8; ++c) acc[r][c] = 0.f;
  int tr = tid >> 4, tc = tid & 15;
  for (int k0 = 0; k0 < 128; k0 += 32) {
    const float4* Wg = (const float4*)(W + k0 * 128);
    float4* Wsv = (float4*)&Ws[0][0];
#pragma unroll
    for (int i = 0; i < 4; ++i) Wsv[tid + 256 * i] = Wg[tid + 256 * i];
#pragma unroll
    for (int p = 0; p < 2; ++p) {
      int rr = p * 32 + (tid >> 3);
      int qq = tid & 7;
      int grow = r0 + rr;
      float4 v = make_float4(0.f, 0.f, 0.f, 0.f);
      if (grow < NN) {
        v = *(const float4*)(A + grow * 128 + k0 + qq * 4);
        if (rowscale) { float s = rowscale[grow]; v.x *= s; v.y *= s; v.z *= s; v.w *= s; }
      }
      As[rr][qq * 4 + 0] = v.x; As[rr][qq * 4 + 1] = v.y;
      As[rr][qq * 4 + 2] = v.z; As[rr][qq * 4 + 3] = v.w;
    }
    __syncthreads();
#pragma unroll
    for (int k = 0; k < 32; ++k) {
      float4 w0 = *(const float4*)&Ws[k][tc * 8];
      float4 w1 = *(const float4*)&Ws[k][tc * 8 + 4];
#pragma unroll
      for (int r = 0; r < 4; ++r) {
        float a = As[tr * 4 + r][k];
        acc[r][0] += a * w0.x; acc[r][1] += a * w0.y; acc[r][2] += a * w0.z; acc[r][3] += a * w0.w;
        acc[r][4] += a * w1.x; acc[r][5] += a * w1.y; acc[r][6] += a * w1.z; acc[r][7] += a * w1.w;
      }
    }
    __syncthreads();
  }
#pragma unroll
  for (int r = 0; r < 4; ++r) {
    int grow = r0 + tr * 4 + r;
    if (grow < NN) {
      float o[8];
#pragma unroll
      for (int c = 0; c < 8; ++c) {
        float v = acc[r][c];
        if (bias) v += bias[tc * 8 + c];
        if (relu) v = fmaxf(v, 0.f);
        o[c] = v;
      }
      *(float4*)(out + grow * 128 + tc * 8)     = make_float4(o[0], o[1], o[2], o[3]);
      *(float4*)(out + grow * 128 + tc * 8 + 4) = make_float4(o[4], o[5], o[6], o[7]);
    }
  }
}

// ---------------- GraphConv aggregation: CSR gather, fused norm+bias+relu ----------------
__global__ __launch_bounds__(128) void gc_agg_kernel(
    const float* __restrict__ m, const int* __restrict__ rowoff,
    const int* __restrict__ indeg, const int* __restrict__ csr_src,
    const float* __restrict__ bias, float* __restrict__ out)
{
  int d = blockIdx.x;
  int c = threadIdx.x;
  int ro = rowoff[d];
  int dg = indeg[d];
  float acc = 0.f;
  for (int j = 0; j < dg; ++j) {
    int s = csr_src[ro + j];
    acc += m[s * 128 + c];
  }
  float ndv = rsqrtf((float)max(dg, 1));
  out[d * 128 + c] = fmaxf(acc * ndv + bias[c], 0.f);
}

// ---------------- Fused GATv2: single-pass online softmax ----------------
__global__ __launch_bounds__(128) void gat_node_kernel(
    const float* __restrict__ fs, const float* __restrict__ fd,
    const float* __restrict__ attn,  // 128 floats: a[h*16+dh]
    const int* __restrict__ rowoff, const int* __restrict__ indeg,
    const int* __restrict__ csr_src,
    float* __restrict__ h)           // in/out [N][128]
{
  int d = blockIdx.x;
  int c = threadIdx.x;
  int ro = rowoff[d];
  int dg = indeg[d];
  float fd_c = fd[d * 128 + c];
  float a_c = attn[c];
  float m = -INFINITY, s_h = 0.f, acc = 0.f;
  for (int j = 0; j < dg; ++j) {
    int s = csr_src[ro + j];
    float fsv = fs[s * 128 + c];
    float x = fsv + fd_c;
    x = x > 0.f ? x : 0.2f * x;
    float y = a_c * x;
    y += __shfl_xor(y, 1);
    y += __shfl_xor(y, 2);
    y += __shfl_xor(y, 4);
    y += __shfl_xor(y, 8);       // all 16 lanes of the head hold the logit
    float newm = fmaxf(m, y);
    float scale = expf(m - newm);    // exp(-inf)=0 on first hit
    float p = expf(y - newm);
    s_h = s_h * scale + p;
    acc = acc * scale + p * fsv;
    m = newm;
  }
  float o = (dg > 0) ? (acc / s_h) : 0.f;
  h[d * 128 + c] = fmaxf(o + h[d * 128 + c], 0.f);
}

// ---------------- pooling + MLP ----------------
__global__ void pool_kernel(const float* __restrict__ h, const int* __restrict__ n2g,
                            unsigned* __restrict__ hg)
{
  int idx = blockIdx.x * blockDim.x + threadIdx.x;
  if (idx >= NN * HIDD) return;
  int r = idx >> 7, c = idx & 127;
  int g = n2g[r];
  atomicMax(&hg[g * 128 + c], __float_as_uint(h[idx]));  // h >= 0 post-relu
}

__global__ __launch_bounds__(128) void mlp_kernel(
    const float* __restrict__ hg,
    const float* __restrict__ Wc1, const float* __restrict__ bc1,
    const float* __restrict__ Wc2, const float* __restrict__ bc2,
    const float* __restrict__ Wc3, const float* __restrict__ bc3,
    float* __restrict__ out)
{
  __shared__ float x[128], z1[128], z2[64];
  int g = blockIdx.x, t = threadIdx.x;
  x[t] = hg[g * 128 + t];
  __syncthreads();
  float acc = bc1[t];
  for (int k = 0; k < 128; ++k) acc += x[k] * Wc1[k * 128 + t];
  z1[t] = fmaxf(acc, 0.f);
  __syncthreads();
  if (t < 64) {
    float a2 = bc2[t];
    for (int k = 0; k < 128; ++k) a2 += z1[k] * Wc2[k * 64 + t];
    z2[t] = fmaxf(a2, 0.f);
  }
  __syncthreads();
#pragma unroll
  for (int p = 0; p < 2; ++p) {
    int c = t + p * 128;
    float a3 = bc3[c];
    for (int k = 0; k < 64; ++k) a3 += z2[k] * Wc3[k * 256 + c];
    out[g * 256 + c] = a3;
  }
}

// ---------------- launch ----------------
extern "C" void kernel_launch(void* const* d_in, const int* in_sizes, int n_in,
                              void* d_out, int out_size, void* d_ws, size_t ws_size,
                              hipStream_t stream)
{
  const float* feature = (const float*)d_in[0];
  const float* W_gc1 = (const float*)d_in[1];
  const float* b_gc1 = (const float*)d_in[2];
  const float* W_gc2 = (const float*)d_in[3];
  const float* b_gc2 = (const float*)d_in[4];
  const float* W_src = (const float*)d_in[5];
  const float* b_src = (const float*)d_in[6];
  const float* W_dst = (const float*)d_in[7];
  const float* b_dst = (const float*)d_in[8];
  const float* attn  = (const float*)d_in[9];
  const float* Wc1 = (const float*)d_in[10];
  const float* bc1 = (const float*)d_in[11];
  const float* Wc2 = (const float*)d_in[12];
  const float* bc2 = (const float*)d_in[13];
  const float* Wc3 = (const float*)d_in[14];
  const float* bc3 = (const float*)d_in[15];
  const int* src = (const int*)d_in[16];
  const int* dst = (const int*)d_in[17];
  const int* n2g = (const int*)d_in[18];

  char* base = (char*)d_ws;
  int* indeg  = (int*)base;            base += NN * sizeof(int);
  int* outdeg = (int*)base;            base += NN * sizeof(int);
  int* rowoff = (int*)base;            base += NN * sizeof(int);
  int* cursor = (int*)base;            base += NN * sizeof(int);
  int* bsum   = (int*)base;            base += 256 * sizeof(int);
  int* csr_src = (int*)base;           base += EE * sizeof(int);
  float* ns = (float*)base;            base += NN * sizeof(float);
  float* h0 = (float*)base;            base += NN * HIDD * sizeof(float);
  float* fs = (float*)base;            base += NN * HIDD * sizeof(float);
  float* fd = (float*)base;            base += NN * HIDD * sizeof(float);
  float* hg = (float*)base;            base += GG * HIDD * sizeof(float);

  // degrees, norms, CSR
  hipMemsetAsync(indeg, 0, 2 * NN * sizeof(int), stream);
  deg_kernel<<<2048, 256, 0, stream>>>(src, dst, outdeg, indeg);
  norm_kernel<<<NBLK, 256, 0, stream>>>(outdeg, ns);
  scan1_kernel<<<NBLK, 256, 0, stream>>>(indeg, rowoff, bsum);
  scan2_kernel<<<1, 256, 0, stream>>>(bsum);
  scan3_kernel<<<NBLK, 256, 0, stream>>>(rowoff, bsum, cursor);
  bin_kernel<<<2048, 256, 0, stream>>>(src, dst, cursor, csr_src);

  const int gemm_grid = (NN + 63) / 64;
  const int ew_grid = NN * HIDD / 256;

  // GraphConv 1 (fs doubles as m-scratch)
  gemm128<<<gemm_grid, 256, 0, stream>>>(feature, W_gc1, nullptr, ns, fs, 0);
  gc_agg_kernel<<<NN, 128, 0, stream>>>(fs, rowoff, indeg, csr_src, b_gc1, h0);
  // GraphConv 2
  gemm128<<<gemm_grid, 256, 0, stream>>>(h0, W_gc2, nullptr, ns, fs, 0);
  gc_agg_kernel<<<NN, 128, 0, stream>>>(fs, rowoff, indeg, csr_src, b_gc2, h0);

  // GATv2 x3
  for (int i = 0; i < 3; ++i) {
    gemm128<<<gemm_grid, 256, 0, stream>>>(h0, W_src + i * HIDD * HIDD, b_src + i * HIDD, nullptr, fs, 0);
    gemm128<<<gemm_grid, 256, 0, stream>>>(h0, W_dst + i * HIDD * HIDD, b_dst + i * HIDD, nullptr, fd, 0);
    gat_node_kernel<<<NN, 128, 0, stream>>>(fs, fd, attn + i * HEADS * DHH,
                                            rowoff, indeg, csr_src, h0);
  }

  // pooling + MLP
  hipMemsetAsync(hg, 0, GG * HIDD * sizeof(float), stream);
  pool_kernel<<<ew_grid, 256, 0, stream>>>(h0, n2g, (unsigned*)hg);
  mlp_kernel<<<GG, 128, 0, stream>>>(hg, Wc1, bc1, Wc2, bc2, Wc3, bc3, (float*)d_out);
}

// Round 4
// 700.165 us; speedup vs baseline: 7.1594x; 1.3393x over previous
//
#include <hip/hip_runtime.h>
#include <hip/hip_bf16.h>

#define NN 50000
#define EE 500000
#define GG 64
#define HIDD 128
#define HEADS 8
#define DHH 16
#define NBLK ((NN + 255) / 256)   // 196
#define RTILES 3128               // ceil(50000/16) rowtiles of 16
#define GEMM_GRID 391             // ceil(50000/128)

typedef __bf16 bf16x8 __attribute__((ext_vector_type(8)));
typedef float f32x4 __attribute__((ext_vector_type(4)));

// ---------------- degree ----------------
__global__ void deg_kernel(const int* __restrict__ src, const int* __restrict__ dst,
                           int* __restrict__ outdeg, int* __restrict__ indeg) {
  int i = blockIdx.x * blockDim.x + threadIdx.x;
  int stride = gridDim.x * blockDim.x;
  for (; i < EE; i += stride) {
    atomicAdd(&outdeg[src[i]], 1);
    atomicAdd(&indeg[dst[i]], 1);
  }
}

__global__ void norm_kernel(const int* __restrict__ outdeg, float* __restrict__ ns) {
  int i = blockIdx.x * blockDim.x + threadIdx.x;
  if (i < NN) ns[i] = rsqrtf((float)max(outdeg[i], 1));
}

// ---------------- hierarchical exclusive scan ----------------
__global__ __launch_bounds__(256) void scan1_kernel(const int* __restrict__ deg,
                                                    int* __restrict__ excl,
                                                    int* __restrict__ bsum) {
  __shared__ int buf[256];
  int t = threadIdx.x;
  int idx = blockIdx.x * 256 + t;
  int v = (idx < NN) ? deg[idx] : 0;
  buf[t] = v;
  __syncthreads();
#pragma unroll
  for (int off = 1; off < 256; off <<= 1) {
    int tmp = (t >= off) ? buf[t - off] : 0;
    __syncthreads();
    buf[t] += tmp;
    __syncthreads();
  }
  if (idx < NN) excl[idx] = buf[t] - v;
  if (t == 255) bsum[blockIdx.x] = buf[255];
}

__global__ __launch_bounds__(256) void scan2_kernel(int* __restrict__ bsum) {
  __shared__ int buf[256];
  int t = threadIdx.x;
  int v = (t < NBLK) ? bsum[t] : 0;
  buf[t] = v;
  __syncthreads();
#pragma unroll
  for (int off = 1; off < 256; off <<= 1) {
    int tmp = (t >= off) ? buf[t - off] : 0;
    __syncthreads();
    buf[t] += tmp;
    __syncthreads();
  }
  if (t < NBLK) bsum[t] = buf[t] - v;
}

__global__ __launch_bounds__(256) void scan3_kernel(int* __restrict__ excl,
                                                    const int* __restrict__ bsum,
                                                    int* __restrict__ cursor) {
  int idx = blockIdx.x * 256 + threadIdx.x;
  if (idx < NN) {
    int v = excl[idx] + bsum[blockIdx.x];
    excl[idx] = v;
    cursor[idx] = v;
  }
}

__global__ void bin_kernel(const int* __restrict__ src, const int* __restrict__ dst,
                           int* __restrict__ cursor, int* __restrict__ csr_src) {
  int i = blockIdx.x * blockDim.x + threadIdx.x;
  int stride = gridDim.x * blockDim.x;
  for (; i < EE; i += stride) {
    int pos = atomicAdd(&cursor[dst[i]], 1);
    csr_src[pos] = src[i];
  }
}

// ---------------- bf16 hi/lo weight split (transposed, k-blocked, pre-swizzled) ----------------
// Wblk[mat]: per k-step (32 k) slab of 8192 elems: [0..4095] hi, [4096..8191] lo.
// Logical elem within slab: L = n*32 + ((k>>3)&3)*8 + (k&7); stored at L ^ ((n&7)<<3).
__global__ __launch_bounds__(256) void split_w_kernel(
    const float* __restrict__ W_gc1, const float* __restrict__ W_gc2,
    const float* __restrict__ W_src, const float* __restrict__ W_dst,
    __bf16* __restrict__ Wblk)
{
  int tid = blockIdx.x * 256 + threadIdx.x;   // 8 * 16384
  int m = tid >> 14;
  int kn = tid & 16383;
  int k = kn >> 7, n = kn & 127;
  const float* Wm = (m == 0) ? W_gc1 : (m == 1) ? W_gc2
                   : (m < 5) ? (W_src + (m - 2) * 16384) : (W_dst + (m - 5) * 16384);
  float v = Wm[kn];
  __bf16 h = (__bf16)v;
  __bf16 l = (__bf16)(v - (float)h);
  int ks = k >> 5;
  int L = n * 32 + ((k >> 3) & 3) * 8 + (k & 7);
  int swz = L ^ ((n & 7) << 3);
  __bf16* dstp = Wblk + m * 32768 + ks * 8192;
  dstp[swz] = h;
  dstp[4096 + swz] = l;
}

// ---------------- bf16 hi/lo input split into MFMA-fragment-blocked layout ----------------
// A_blk: rowtile (16 rows) x 2048 elems; within: kstep(k>>5)*512 + lane*8 + (k&7),
// lane = (row&15) + ((k>>3)&3)*16.  Rows >= NN zero-filled.
__global__ __launch_bounds__(256) void split_h_kernel(
    const float* __restrict__ X, const float* __restrict__ scale,
    __bf16* __restrict__ Ah, __bf16* __restrict__ Al)
{
  int tid = blockIdx.x * 256 + threadIdx.x;   // RTILES*16*16 = 800768 exact
  int row = tid >> 4, kc = tid & 15;
  float v[8];
  if (row < NN) {
    const float4* p = (const float4*)(X + row * 128 + kc * 8);
    float4 a = p[0], b = p[1];
    float s = scale ? scale[row] : 1.f;
    v[0] = a.x * s; v[1] = a.y * s; v[2] = a.z * s; v[3] = a.w * s;
    v[4] = b.x * s; v[5] = b.y * s; v[6] = b.z * s; v[7] = b.w * s;
  } else {
#pragma unroll
    for (int i = 0; i < 8; ++i) v[i] = 0.f;
  }
  bf16x8 hi, lo;
#pragma unroll
  for (int i = 0; i < 8; ++i) {
    __bf16 h = (__bf16)v[i];
    hi[i] = h;
    lo[i] = (__bf16)(v[i] - (float)h);
  }
  int off = (row >> 4) * 2048 + (kc >> 2) * 512 + ((row & 15) + (kc & 3) * 16) * 8;
  *(bf16x8*)(Ah + off) = hi;
  *(bf16x8*)(Al + off) = lo;
}

// ---------------- bf16x3 MFMA GEMM: out[N][128] = A @ W (+bias) ----------------
// block: 256 thr = 4 waves (2x2), tile 128 rows x 128 cols; wave: 64r x 64c = 4x4
// 16x16 tiles; K = 128 in 4 steps of 32. W slab staged in LDS (16 KB, swizzled).
__global__ __launch_bounds__(256) void gemm_mfma(
    const __bf16* __restrict__ Ah, const __bf16* __restrict__ Al,
    const __bf16* __restrict__ Wmat,   // this matrix's 32768-elem block
    const float* __restrict__ bias,    // may be null
    float* __restrict__ out)
{
  __shared__ __bf16 wt[8192];          // 16 KB: [0..4095] hi, [4096..] lo
  int tid = threadIdx.x;
  int wid = tid >> 6, lane = tid & 63;
  int wr = wid >> 1, wc = wid & 1;
  int l15 = lane & 15, l4 = lane >> 4;
  f32x4 acc[4][4];
#pragma unroll
  for (int a = 0; a < 4; ++a)
#pragma unroll
    for (int b = 0; b < 4; ++b) acc[a][b] = (f32x4){0.f, 0.f, 0.f, 0.f};
  int rowtile0 = blockIdx.x * 8 + wr * 4;

  for (int ks = 0; ks < 4; ++ks) {
    // stage this k-step's W slab (global layout already swizzled+linear)
    {
      const bf16x8* g = (const bf16x8*)(Wmat + ks * 8192);
      bf16x8* l = (bf16x8*)wt;
      l[tid]       = g[tid];
      l[tid + 256] = g[tid + 256];
      l[tid + 512] = g[tid + 512];
      l[tid + 768] = g[tid + 768];
    }
    bf16x8 ah[4], al[4];
#pragma unroll
    for (int rt = 0; rt < 4; ++rt) {
      int off = (rowtile0 + rt) * 2048 + ks * 512 + lane * 8;
      ah[rt] = *(const bf16x8*)(Ah + off);
      al[rt] = *(const bf16x8*)(Al + off);
    }
    __syncthreads();
#pragma unroll
    for (int ct = 0; ct < 4; ++ct) {
      int n = wc * 64 + ct * 16 + l15;
      int ei = (n * 32 + l4 * 8) ^ ((n & 7) << 3);
      bf16x8 bh = *(const bf16x8*)(wt + ei);
      bf16x8 bl = *(const bf16x8*)(wt + 4096 + ei);
#pragma unroll
      for (int rt = 0; rt < 4; ++rt) {
        acc[rt][ct] = __builtin_amdgcn_mfma_f32_16x16x32_bf16(ah[rt], bh, acc[rt][ct], 0, 0, 0);
        acc[rt][ct] = __builtin_amdgcn_mfma_f32_16x16x32_bf16(ah[rt], bl, acc[rt][ct], 0, 0, 0);
        acc[rt][ct] = __builtin_amdgcn_mfma_f32_16x16x32_bf16(al[rt], bh, acc[rt][ct], 0, 0, 0);
      }
    }
    __syncthreads();
  }
  // epilogue: C/D col = lane&15, row = (lane>>4)*4 + reg
  int rowbase = blockIdx.x * 128 + wr * 64;
#pragma unroll
  for (int ct = 0; ct < 4; ++ct) {
    int col = wc * 64 + ct * 16 + l15;
    float b = bias ? bias[col] : 0.f;
#pragma unroll
    for (int rt = 0; rt < 4; ++rt) {
#pragma unroll
      for (int r = 0; r < 4; ++r) {
        int row = rowbase + rt * 16 + l4 * 4 + r;
        if (row < NN) out[row * 128 + col] = acc[rt][ct][r] + b;
      }
    }
  }
}

// ---------------- GraphConv aggregation: CSR gather, fused norm+bias+relu ----------------
__global__ __launch_bounds__(128) void gc_agg_kernel(
    const float* __restrict__ m, const int* __restrict__ rowoff,
    const int* __restrict__ indeg, const int* __restrict__ csr_src,
    const float* __restrict__ bias, float* __restrict__ out)
{
  int d = blockIdx.x;
  int c = threadIdx.x;
  int ro = rowoff[d];
  int dg = indeg[d];
  float acc = 0.f;
  for (int j = 0; j < dg; ++j) {
    int s = csr_src[ro + j];
    acc += m[s * 128 + c];
  }
  float ndv = rsqrtf((float)max(dg, 1));
  out[d * 128 + c] = fmaxf(acc * ndv + bias[c], 0.f);
}

// ---------------- Fused GATv2: single-pass online softmax (fast exp) ----------------
__global__ __launch_bounds__(128) void gat_node_kernel(
    const float* __restrict__ fs, const float* __restrict__ fd,
    const float* __restrict__ attn,
    const int* __restrict__ rowoff, const int* __restrict__ indeg,
    const int* __restrict__ csr_src,
    float* __restrict__ h)
{
  int d = blockIdx.x;
  int c = threadIdx.x;
  int ro = rowoff[d];
  int dg = indeg[d];
  float fd_c = fd[d * 128 + c];
  float a_c = attn[c];
  float m = -INFINITY, s_h = 0.f, acc = 0.f;
  for (int j = 0; j < dg; ++j) {
    int s = csr_src[ro + j];
    float fsv = fs[s * 128 + c];
    float x = fsv + fd_c;
    x = x > 0.f ? x : 0.2f * x;
    float y = a_c * x;
    y += __shfl_xor(y, 1);
    y += __shfl_xor(y, 2);
    y += __shfl_xor(y, 4);
    y += __shfl_xor(y, 8);
    float newm = fmaxf(m, y);
    float scale = __expf(m - newm);
    float p = __expf(y - newm);
    s_h = s_h * scale + p;
    acc = acc * scale + p * fsv;
    m = newm;
  }
  float o = (dg > 0) ? (acc / s_h) : 0.f;
  h[d * 128 + c] = fmaxf(o + h[d * 128 + c], 0.f);
}

// ---------------- pooling (n2g sorted: per-graph range + few atomics) ----------------
__global__ __launch_bounds__(128) void pool_kernel(const float* __restrict__ h,
                                                   const int* __restrict__ n2g,
                                                   unsigned* __restrict__ hg)
{
  int g = blockIdx.x >> 3, chunk = blockIdx.x & 7, c = threadIdx.x;
  int lo = 0, hi = NN;
  while (lo < hi) { int mid = (lo + hi) >> 1; if (n2g[mid] < g) lo = mid + 1; else hi = mid; }
  int start = lo;
  hi = NN;
  while (lo < hi) { int mid = (lo + hi) >> 1; if (n2g[mid] < g + 1) lo = mid + 1; else hi = mid; }
  int end = lo;
  int len = end - start;
  int s = start + (int)(((long long)len * chunk) >> 3);
  int e = start + (int)(((long long)len * (chunk + 1)) >> 3);
  float m = 0.f;   // h >= 0 post-relu
  for (int r = s; r < e; ++r) m = fmaxf(m, h[r * 128 + c]);
  atomicMax(&hg[g * 128 + c], __float_as_uint(m));
}

__global__ __launch_bounds__(128) void mlp_kernel(
    const float* __restrict__ hg,
    const float* __restrict__ Wc1, const float* __restrict__ bc1,
    const float* __restrict__ Wc2, const float* __restrict__ bc2,
    const float* __restrict__ Wc3, const float* __restrict__ bc3,
    float* __restrict__ out)
{
  __shared__ float x[128], z1[128], z2[64];
  int g = blockIdx.x, t = threadIdx.x;
  x[t] = hg[g * 128 + t];
  __syncthreads();
  float acc = bc1[t];
  for (int k = 0; k < 128; ++k) acc += x[k] * Wc1[k * 128 + t];
  z1[t] = fmaxf(acc, 0.f);
  __syncthreads();
  if (t < 64) {
    float a2 = bc2[t];
    for (int k = 0; k < 128; ++k) a2 += z1[k] * Wc2[k * 64 + t];
    z2[t] = fmaxf(a2, 0.f);
  }
  __syncthreads();
#pragma unroll
  for (int p = 0; p < 2; ++p) {
    int c = t + p * 128;
    float a3 = bc3[c];
    for (int k = 0; k < 64; ++k) a3 += z2[k] * Wc3[k * 256 + c];
    out[g * 256 + c] = a3;
  }
}

// ---------------- launch ----------------
extern "C" void kernel_launch(void* const* d_in, const int* in_sizes, int n_in,
                              void* d_out, int out_size, void* d_ws, size_t ws_size,
                              hipStream_t stream)
{
  const float* feature = (const float*)d_in[0];
  const float* W_gc1 = (const float*)d_in[1];
  const float* b_gc1 = (const float*)d_in[2];
  const float* W_gc2 = (const float*)d_in[3];
  const float* b_gc2 = (const float*)d_in[4];
  const float* W_src = (const float*)d_in[5];
  const float* b_src = (const float*)d_in[6];
  const float* W_dst = (const float*)d_in[7];
  const float* b_dst = (const float*)d_in[8];
  const float* attn  = (const float*)d_in[9];
  const float* Wc1 = (const float*)d_in[10];
  const float* bc1 = (const float*)d_in[11];
  const float* Wc2 = (const float*)d_in[12];
  const float* bc2 = (const float*)d_in[13];
  const float* Wc3 = (const float*)d_in[14];
  const float* bc3 = (const float*)d_in[15];
  const int* src = (const int*)d_in[16];
  const int* dst = (const int*)d_in[17];
  const int* n2g = (const int*)d_in[18];

  char* base = (char*)d_ws;
  int* indeg  = (int*)base;            base += NN * sizeof(int);
  int* outdeg = (int*)base;            base += NN * sizeof(int);
  int* rowoff = (int*)base;            base += NN * sizeof(int);
  int* cursor = (int*)base;            base += NN * sizeof(int);
  int* bsum   = (int*)base;            base += 256 * sizeof(int);
  int* csr_src = (int*)base;           base += EE * sizeof(int);
  float* ns = (float*)base;            base += NN * sizeof(float);
  float* h0 = (float*)base;            base += (size_t)NN * HIDD * sizeof(float);
  float* fs = (float*)base;            base += (size_t)NN * HIDD * sizeof(float);
  float* fd = (float*)base;            base += (size_t)NN * HIDD * sizeof(float);
  __bf16* Ah = (__bf16*)base;          base += (size_t)RTILES * 2048 * sizeof(__bf16);
  __bf16* Al = (__bf16*)base;          base += (size_t)RTILES * 2048 * sizeof(__bf16);
  __bf16* Wblk = (__bf16*)base;        base += (size_t)8 * 32768 * sizeof(__bf16);
  float* hg = (float*)base;            base += GG * HIDD * sizeof(float);

  // degrees, norms, CSR
  hipMemsetAsync(indeg, 0, 2 * NN * sizeof(int), stream);
  deg_kernel<<<2048, 256, 0, stream>>>(src, dst, outdeg, indeg);
  norm_kernel<<<NBLK, 256, 0, stream>>>(outdeg, ns);
  scan1_kernel<<<NBLK, 256, 0, stream>>>(indeg, rowoff, bsum);
  scan2_kernel<<<1, 256, 0, stream>>>(bsum);
  scan3_kernel<<<NBLK, 256, 0, stream>>>(rowoff, bsum, cursor);
  bin_kernel<<<2048, 256, 0, stream>>>(src, dst, cursor, csr_src);

  // weight split (all 8 matrices)
  split_w_kernel<<<512, 256, 0, stream>>>(W_gc1, W_gc2, W_src, W_dst, Wblk);

  const int split_grid = RTILES * 16 * 16 / 256;   // 3128

  // GraphConv 1: m = (feature*ns) @ W_gc1  (m in fd)
  split_h_kernel<<<split_grid, 256, 0, stream>>>(feature, ns, Ah, Al);
  gemm_mfma<<<GEMM_GRID, 256, 0, stream>>>(Ah, Al, Wblk + 0 * 32768, nullptr, fd);
  gc_agg_kernel<<<NN, 128, 0, stream>>>(fd, rowoff, indeg, csr_src, b_gc1, h0);
  // GraphConv 2
  split_h_kernel<<<split_grid, 256, 0, stream>>>(h0, ns, Ah, Al);
  gemm_mfma<<<GEMM_GRID, 256, 0, stream>>>(Ah, Al, Wblk + 1 * 32768, nullptr, fd);
  gc_agg_kernel<<<NN, 128, 0, stream>>>(fd, rowoff, indeg, csr_src, b_gc2, h0);

  // GATv2 x3
  for (int i = 0; i < 3; ++i) {
    split_h_kernel<<<split_grid, 256, 0, stream>>>(h0, nullptr, Ah, Al);
    gemm_mfma<<<GEMM_GRID, 256, 0, stream>>>(Ah, Al, Wblk + (2 + i) * 32768, b_src + i * HIDD, fs);
    gemm_mfma<<<GEMM_GRID, 256, 0, stream>>>(Ah, Al, Wblk + (5 + i) * 32768, b_dst + i * HIDD, fd);
    gat_node_kernel<<<NN, 128, 0, stream>>>(fs, fd, attn + i * HEADS * DHH,
                                            rowoff, indeg, csr_src, h0);
  }

  // pooling + MLP
  hipMemsetAsync(hg, 0, GG * HIDD * sizeof(float), stream);
  pool_kernel<<<GG * 8, 128, 0, stream>>>(h0, n2g, (unsigned*)hg);
  mlp_kernel<<<GG, 128, 0, stream>>>(hg, Wc1, bc1, Wc2, bc2, Wc3, bc3, (float*)d_out);
}

// Round 5
// 593.761 us; speedup vs baseline: 8.4424x; 1.1792x over previous
//
#include <hip/hip_runtime.h>
#include <hip/hip_bf16.h>

#define NN 50000
#define EE 500000
#define GG 64
#define HIDD 128
#define HEADS 8
#define DHH 16
#define NBLK ((NN + 255) / 256)   // 196
#define RTILES 3128               // ceil(50000/16) rowtiles of 16
#define GEMM_GRID 391             // ceil(50000/128)

typedef __bf16 bf16x8 __attribute__((ext_vector_type(8)));
typedef float f32x4 __attribute__((ext_vector_type(4)));

// 16-lane (DPP row) ring-rotation sum reduce: all 16 lanes end with the row sum.
__device__ inline float rowsum16(float y) {
  int t;
  t = __builtin_amdgcn_mov_dpp(__float_as_int(y), 0x121, 0xF, 0xF, true); y += __int_as_float(t); // ror:1
  t = __builtin_amdgcn_mov_dpp(__float_as_int(y), 0x122, 0xF, 0xF, true); y += __int_as_float(t); // ror:2
  t = __builtin_amdgcn_mov_dpp(__float_as_int(y), 0x124, 0xF, 0xF, true); y += __int_as_float(t); // ror:4
  t = __builtin_amdgcn_mov_dpp(__float_as_int(y), 0x128, 0xF, 0xF, true); y += __int_as_float(t); // ror:8
  return y;
}

// blocked bf16 fragment offset for element (row, 8-col-group kc)
__device__ inline int frag_off(int row, int kc) {
  return (row >> 4) * 2048 + (kc >> 2) * 512 + ((row & 15) + (kc & 3) * 16) * 8;
}

// ---------------- degree ----------------
__global__ void deg_kernel(const int* __restrict__ src, const int* __restrict__ dst,
                           int* __restrict__ outdeg, int* __restrict__ indeg) {
  int i = blockIdx.x * blockDim.x + threadIdx.x;
  int stride = gridDim.x * blockDim.x;
  for (; i < EE; i += stride) {
    atomicAdd(&outdeg[src[i]], 1);
    atomicAdd(&indeg[dst[i]], 1);
  }
}

__global__ void norm_kernel(const int* __restrict__ outdeg, float* __restrict__ ns) {
  int i = blockIdx.x * blockDim.x + threadIdx.x;
  if (i < NN) ns[i] = rsqrtf((float)max(outdeg[i], 1));
}

// ---------------- hierarchical exclusive scan ----------------
__global__ __launch_bounds__(256) void scan1_kernel(const int* __restrict__ deg,
                                                    int* __restrict__ excl,
                                                    int* __restrict__ bsum) {
  __shared__ int buf[256];
  int t = threadIdx.x;
  int idx = blockIdx.x * 256 + t;
  int v = (idx < NN) ? deg[idx] : 0;
  buf[t] = v;
  __syncthreads();
#pragma unroll
  for (int off = 1; off < 256; off <<= 1) {
    int tmp = (t >= off) ? buf[t - off] : 0;
    __syncthreads();
    buf[t] += tmp;
    __syncthreads();
  }
  if (idx < NN) excl[idx] = buf[t] - v;
  if (t == 255) bsum[blockIdx.x] = buf[255];
}

__global__ __launch_bounds__(256) void scan2_kernel(int* __restrict__ bsum) {
  __shared__ int buf[256];
  int t = threadIdx.x;
  int v = (t < NBLK) ? bsum[t] : 0;
  buf[t] = v;
  __syncthreads();
#pragma unroll
  for (int off = 1; off < 256; off <<= 1) {
    int tmp = (t >= off) ? buf[t - off] : 0;
    __syncthreads();
    buf[t] += tmp;
    __syncthreads();
  }
  if (t < NBLK) bsum[t] = buf[t] - v;
}

__global__ __launch_bounds__(256) void scan3_kernel(int* __restrict__ excl,
                                                    const int* __restrict__ bsum,
                                                    int* __restrict__ cursor) {
  int idx = blockIdx.x * 256 + threadIdx.x;
  if (idx < NN) {
    int v = excl[idx] + bsum[blockIdx.x];
    excl[idx] = v;
    cursor[idx] = v;
  }
}

__global__ void bin_kernel(const int* __restrict__ src, const int* __restrict__ dst,
                           int* __restrict__ cursor, int* __restrict__ csr_src) {
  int i = blockIdx.x * blockDim.x + threadIdx.x;
  int stride = gridDim.x * blockDim.x;
  for (; i < EE; i += stride) {
    int pos = atomicAdd(&cursor[dst[i]], 1);
    csr_src[pos] = src[i];
  }
}

// ---------------- bf16 hi/lo weight split (transposed, k-blocked, pre-swizzled) ----------------
__global__ __launch_bounds__(256) void split_w_kernel(
    const float* __restrict__ W_gc1, const float* __restrict__ W_gc2,
    const float* __restrict__ W_src, const float* __restrict__ W_dst,
    __bf16* __restrict__ Wblk)
{
  int tid = blockIdx.x * 256 + threadIdx.x;   // 8 * 16384
  int m = tid >> 14;
  int kn = tid & 16383;
  int k = kn >> 7, n = kn & 127;
  const float* Wm = (m == 0) ? W_gc1 : (m == 1) ? W_gc2
                   : (m < 5) ? (W_src + (m - 2) * 16384) : (W_dst + (m - 5) * 16384);
  float v = Wm[kn];
  __bf16 h = (__bf16)v;
  __bf16 l = (__bf16)(v - (float)h);
  int ks = k >> 5;
  int L = n * 32 + ((k >> 3) & 3) * 8 + (k & 7);
  int swz = L ^ ((n & 7) << 3);
  __bf16* dstp = Wblk + m * 32768 + ks * 8192;
  dstp[swz] = h;
  dstp[4096 + swz] = l;
}

// ---------------- bf16 hi/lo input split (feature only) ----------------
__global__ __launch_bounds__(256) void split_h_kernel(
    const float* __restrict__ X, const float* __restrict__ scale,
    __bf16* __restrict__ Ah, __bf16* __restrict__ Al)
{
  int tid = blockIdx.x * 256 + threadIdx.x;   // RTILES*16*16
  int row = tid >> 4, kc = tid & 15;
  float v[8];
  if (row < NN) {
    const float4* p = (const float4*)(X + row * 128 + kc * 8);
    float4 a = p[0], b = p[1];
    float s = scale ? scale[row] : 1.f;
    v[0] = a.x * s; v[1] = a.y * s; v[2] = a.z * s; v[3] = a.w * s;
    v[4] = b.x * s; v[5] = b.y * s; v[6] = b.z * s; v[7] = b.w * s;
  } else {
#pragma unroll
    for (int i = 0; i < 8; ++i) v[i] = 0.f;
  }
  bf16x8 hi, lo;
#pragma unroll
  for (int i = 0; i < 8; ++i) {
    __bf16 h = (__bf16)v[i];
    hi[i] = h;
    lo[i] = (__bf16)(v[i] - (float)h);
  }
  int off = frag_off(row, kc);
  *(bf16x8*)(Ah + off) = hi;
  *(bf16x8*)(Al + off) = lo;
}

// ---------------- bf16x3 MFMA GEMM ----------------
__global__ __launch_bounds__(256) void gemm_mfma(
    const __bf16* __restrict__ Ah, const __bf16* __restrict__ Al,
    const __bf16* __restrict__ Wmat, const float* __restrict__ bias,
    float* __restrict__ out)
{
  __shared__ __bf16 wt[8192];
  int tid = threadIdx.x;
  int wid = tid >> 6, lane = tid & 63;
  int wr = wid >> 1, wc = wid & 1;
  int l15 = lane & 15, l4 = lane >> 4;
  f32x4 acc[4][4];
#pragma unroll
  for (int a = 0; a < 4; ++a)
#pragma unroll
    for (int b = 0; b < 4; ++b) acc[a][b] = (f32x4){0.f, 0.f, 0.f, 0.f};
  int rowtile0 = blockIdx.x * 8 + wr * 4;

  for (int ks = 0; ks < 4; ++ks) {
    {
      const bf16x8* g = (const bf16x8*)(Wmat + ks * 8192);
      bf16x8* l = (bf16x8*)wt;
      l[tid]       = g[tid];
      l[tid + 256] = g[tid + 256];
      l[tid + 512] = g[tid + 512];
      l[tid + 768] = g[tid + 768];
    }
    bf16x8 ah[4], al[4];
#pragma unroll
    for (int rt = 0; rt < 4; ++rt) {
      int off = (rowtile0 + rt) * 2048 + ks * 512 + lane * 8;
      ah[rt] = *(const bf16x8*)(Ah + off);
      al[rt] = *(const bf16x8*)(Al + off);
    }
    __syncthreads();
#pragma unroll
    for (int ct = 0; ct < 4; ++ct) {
      int n = wc * 64 + ct * 16 + l15;
      int ei = (n * 32 + l4 * 8) ^ ((n & 7) << 3);
      bf16x8 bh = *(const bf16x8*)(wt + ei);
      bf16x8 bl = *(const bf16x8*)(wt + 4096 + ei);
#pragma unroll
      for (int rt = 0; rt < 4; ++rt) {
        acc[rt][ct] = __builtin_amdgcn_mfma_f32_16x16x32_bf16(ah[rt], bh, acc[rt][ct], 0, 0, 0);
        acc[rt][ct] = __builtin_amdgcn_mfma_f32_16x16x32_bf16(ah[rt], bl, acc[rt][ct], 0, 0, 0);
        acc[rt][ct] = __builtin_amdgcn_mfma_f32_16x16x32_bf16(al[rt], bh, acc[rt][ct], 0, 0, 0);
      }
    }
    __syncthreads();
  }
  int rowbase = blockIdx.x * 128 + wr * 64;
#pragma unroll
  for (int ct = 0; ct < 4; ++ct) {
    int col = wc * 64 + ct * 16 + l15;
    float b = bias ? bias[col] : 0.f;
#pragma unroll
    for (int rt = 0; rt < 4; ++rt) {
#pragma unroll
      for (int r = 0; r < 4; ++r) {
        int row = rowbase + rt * 16 + l4 * 4 + r;
        if (row < NN) out[row * 128 + col] = acc[rt][ct][r] + b;
      }
    }
  }
}

// ---------------- GraphConv aggregation: CSR gather ×4-unrolled, fused split ----------------
__global__ __launch_bounds__(128) void gc_agg_kernel(
    const float* __restrict__ m, const int* __restrict__ rowoff,
    const int* __restrict__ indeg, const int* __restrict__ csr_src,
    const float* __restrict__ bias, const float* __restrict__ nsrow,
    float* __restrict__ out,          // null = skip fp32 write
    __bf16* __restrict__ Ah, __bf16* __restrict__ Al)   // null = skip split
{
  __shared__ float buf[128];
  int d = blockIdx.x, c = threadIdx.x;
  int ro = rowoff[d], dg = indeg[d];
  float a0 = 0.f, a1 = 0.f, a2 = 0.f, a3 = 0.f;
  int j = 0;
  for (; j + 4 <= dg; j += 4) {
    int s0 = csr_src[ro + j], s1 = csr_src[ro + j + 1];
    int s2 = csr_src[ro + j + 2], s3 = csr_src[ro + j + 3];
    a0 += m[s0 * 128 + c]; a1 += m[s1 * 128 + c];
    a2 += m[s2 * 128 + c]; a3 += m[s3 * 128 + c];
  }
  for (; j < dg; ++j) a0 += m[csr_src[ro + j] * 128 + c];
  float acc = (a0 + a1) + (a2 + a3);
  float ndv = rsqrtf((float)max(dg, 1));
  float v = fmaxf(acc * ndv + bias[c], 0.f);
  if (out) out[d * 128 + c] = v;
  if (Ah) {
    buf[c] = nsrow ? v * nsrow[d] : v;
    __syncthreads();
    if (c < 32) {
      int kc = c & 15;
      int off = frag_off(d, kc);
      bf16x8 pk;
      if (c < 16) {
#pragma unroll
        for (int i = 0; i < 8; ++i) pk[i] = (__bf16)buf[kc * 8 + i];
        *(bf16x8*)(Ah + off) = pk;
      } else {
#pragma unroll
        for (int i = 0; i < 8; ++i) {
          float x = buf[kc * 8 + i];
          __bf16 hh = (__bf16)x;
          pk[i] = (__bf16)(x - (float)hh);
        }
        *(bf16x8*)(Al + off) = pk;
      }
    }
  }
}

// ---------------- Fused GATv2: DPP logit reduce, 2-way online softmax, fused split ----------------
__global__ __launch_bounds__(128) void gat_node_kernel(
    const float* __restrict__ fs, const float* __restrict__ fd,
    const float* __restrict__ attn,
    const int* __restrict__ rowoff, const int* __restrict__ indeg,
    const int* __restrict__ csr_src,
    float* __restrict__ h,            // in/out
    __bf16* __restrict__ Ah, __bf16* __restrict__ Al)   // null = skip split
{
  __shared__ float buf[128];
  int d = blockIdx.x, c = threadIdx.x;
  int ro = rowoff[d], dg = indeg[d];
  float fd_c = fd[d * 128 + c];
  float a_c = attn[c];
  float mA = -INFINITY, sA = 0.f, aA = 0.f;
  float mB = -INFINITY, sB = 0.f, aB = 0.f;
  int j = 0;
  for (; j + 2 <= dg; j += 2) {
    int s0 = csr_src[ro + j], s1 = csr_src[ro + j + 1];
    float f0 = fs[s0 * 128 + c], f1 = fs[s1 * 128 + c];
    float x0 = f0 + fd_c; x0 = fmaxf(x0, 0.f) + 0.2f * fminf(x0, 0.f);
    float x1 = f1 + fd_c; x1 = fmaxf(x1, 0.f) + 0.2f * fminf(x1, 0.f);
    float y0 = rowsum16(a_c * x0);
    float y1 = rowsum16(a_c * x1);
    float nm = fmaxf(mA, y0);
    float sc = __expf(mA - nm), p = __expf(y0 - nm);
    sA = sA * sc + p; aA = aA * sc + p * f0; mA = nm;
    nm = fmaxf(mB, y1);
    sc = __expf(mB - nm); p = __expf(y1 - nm);
    sB = sB * sc + p; aB = aB * sc + p * f1; mB = nm;
  }
  if (j < dg) {
    int s0 = csr_src[ro + j];
    float f0 = fs[s0 * 128 + c];
    float x0 = f0 + fd_c; x0 = fmaxf(x0, 0.f) + 0.2f * fminf(x0, 0.f);
    float y0 = rowsum16(a_c * x0);
    float nm = fmaxf(mA, y0);
    float sc = __expf(mA - nm), p = __expf(y0 - nm);
    sA = sA * sc + p; aA = aA * sc + p * f0; mA = nm;
  }
  float o = 0.f;
  if (dg > 0) {
    float M = fmaxf(mA, mB);
    float eA = __expf(mA - M), eB = __expf(mB - M);   // exp(-inf)=0 handles dg==1
    o = (aA * eA + aB * eB) / (sA * eA + sB * eB);
  }
  float v = fmaxf(o + h[d * 128 + c], 0.f);
  h[d * 128 + c] = v;
  if (Ah) {
    buf[c] = v;
    __syncthreads();
    if (c < 32) {
      int kc = c & 15;
      int off = frag_off(d, kc);
      bf16x8 pk;
      if (c < 16) {
#pragma unroll
        for (int i = 0; i < 8; ++i) pk[i] = (__bf16)buf[kc * 8 + i];
        *(bf16x8*)(Ah + off) = pk;
      } else {
#pragma unroll
        for (int i = 0; i < 8; ++i) {
          float x = buf[kc * 8 + i];
          __bf16 hh = (__bf16)x;
          pk[i] = (__bf16)(x - (float)hh);
        }
        *(bf16x8*)(Al + off) = pk;
      }
    }
  }
}

// ---------------- pooling (n2g sorted: per-graph range + few atomics) ----------------
__global__ __launch_bounds__(128) void pool_kernel(const float* __restrict__ h,
                                                   const int* __restrict__ n2g,
                                                   unsigned* __restrict__ hg)
{
  int g = blockIdx.x >> 3, chunk = blockIdx.x & 7, c = threadIdx.x;
  int lo = 0, hi = NN;
  while (lo < hi) { int mid = (lo + hi) >> 1; if (n2g[mid] < g) lo = mid + 1; else hi = mid; }
  int start = lo;
  hi = NN;
  while (lo < hi) { int mid = (lo + hi) >> 1; if (n2g[mid] < g + 1) lo = mid + 1; else hi = mid; }
  int end = lo;
  int len = end - start;
  int s = start + (int)(((long long)len * chunk) >> 3);
  int e = start + (int)(((long long)len * (chunk + 1)) >> 3);
  float m = 0.f;
  for (int r = s; r < e; ++r) m = fmaxf(m, h[r * 128 + c]);
  atomicMax(&hg[g * 128 + c], __float_as_uint(m));
}

__global__ __launch_bounds__(128) void mlp_kernel(
    const float* __restrict__ hg,
    const float* __restrict__ Wc1, const float* __restrict__ bc1,
    const float* __restrict__ Wc2, const float* __restrict__ bc2,
    const float* __restrict__ Wc3, const float* __restrict__ bc3,
    float* __restrict__ out)
{
  __shared__ float x[128], z1[128], z2[64];
  int g = blockIdx.x, t = threadIdx.x;
  x[t] = hg[g * 128 + t];
  __syncthreads();
  float acc = bc1[t];
  for (int k = 0; k < 128; ++k) acc += x[k] * Wc1[k * 128 + t];
  z1[t] = fmaxf(acc, 0.f);
  __syncthreads();
  if (t < 64) {
    float a2 = bc2[t];
    for (int k = 0; k < 128; ++k) a2 += z1[k] * Wc2[k * 64 + t];
    z2[t] = fmaxf(a2, 0.f);
  }
  __syncthreads();
#pragma unroll
  for (int p = 0; p < 2; ++p) {
    int c = t + p * 128;
    float a3 = bc3[c];
    for (int k = 0; k < 64; ++k) a3 += z2[k] * Wc3[k * 256 + c];
    out[g * 256 + c] = a3;
  }
}

// ---------------- launch ----------------
extern "C" void kernel_launch(void* const* d_in, const int* in_sizes, int n_in,
                              void* d_out, int out_size, void* d_ws, size_t ws_size,
                              hipStream_t stream)
{
  const float* feature = (const float*)d_in[0];
  const float* W_gc1 = (const float*)d_in[1];
  const float* b_gc1 = (const float*)d_in[2];
  const float* W_gc2 = (const float*)d_in[3];
  const float* b_gc2 = (const float*)d_in[4];
  const float* W_src = (const float*)d_in[5];
  const float* b_src = (const float*)d_in[6];
  const float* W_dst = (const float*)d_in[7];
  const float* b_dst = (const float*)d_in[8];
  const float* attn  = (const float*)d_in[9];
  const float* Wc1 = (const float*)d_in[10];
  const float* bc1 = (const float*)d_in[11];
  const float* Wc2 = (const float*)d_in[12];
  const float* bc2 = (const float*)d_in[13];
  const float* Wc3 = (const float*)d_in[14];
  const float* bc3 = (const float*)d_in[15];
  const int* src = (const int*)d_in[16];
  const int* dst = (const int*)d_in[17];
  const int* n2g = (const int*)d_in[18];

  char* base = (char*)d_ws;
  int* indeg  = (int*)base;            base += NN * sizeof(int);
  int* outdeg = (int*)base;            base += NN * sizeof(int);
  int* rowoff = (int*)base;            base += NN * sizeof(int);
  int* cursor = (int*)base;            base += NN * sizeof(int);
  int* bsum   = (int*)base;            base += 256 * sizeof(int);
  int* csr_src = (int*)base;           base += EE * sizeof(int);
  float* ns = (float*)base;            base += NN * sizeof(float);
  float* h0 = (float*)base;            base += (size_t)NN * HIDD * sizeof(float);
  float* fs = (float*)base;            base += (size_t)NN * HIDD * sizeof(float);
  float* fd = (float*)base;            base += (size_t)NN * HIDD * sizeof(float);
  __bf16* Ah = (__bf16*)base;          base += (size_t)RTILES * 2048 * sizeof(__bf16);
  __bf16* Al = (__bf16*)base;          base += (size_t)RTILES * 2048 * sizeof(__bf16);
  __bf16* Wblk = (__bf16*)base;        base += (size_t)8 * 32768 * sizeof(__bf16);
  float* hg = (float*)base;            base += GG * HIDD * sizeof(float);

  // degrees, norms, CSR
  hipMemsetAsync(indeg, 0, 2 * NN * sizeof(int), stream);
  deg_kernel<<<2048, 256, 0, stream>>>(src, dst, outdeg, indeg);
  norm_kernel<<<NBLK, 256, 0, stream>>>(outdeg, ns);
  scan1_kernel<<<NBLK, 256, 0, stream>>>(indeg, rowoff, bsum);
  scan2_kernel<<<1, 256, 0, stream>>>(bsum);
  scan3_kernel<<<NBLK, 256, 0, stream>>>(rowoff, bsum, cursor);
  bin_kernel<<<2048, 256, 0, stream>>>(src, dst, cursor, csr_src);

  // weight split (all 8 matrices)
  split_w_kernel<<<512, 256, 0, stream>>>(W_gc1, W_gc2, W_src, W_dst, Wblk);

  const int split_grid = RTILES * 16 * 16 / 256;

  // GC1: split(feature*ns) -> gemm -> agg (writes only next split, scaled by ns)
  split_h_kernel<<<split_grid, 256, 0, stream>>>(feature, ns, Ah, Al);
  gemm_mfma<<<GEMM_GRID, 256, 0, stream>>>(Ah, Al, Wblk + 0 * 32768, nullptr, fd);
  gc_agg_kernel<<<NN, 128, 0, stream>>>(fd, rowoff, indeg, csr_src, b_gc1, ns,
                                        nullptr, Ah, Al);
  // GC2: gemm -> agg (writes h0 + unscaled split for GAT1)
  gemm_mfma<<<GEMM_GRID, 256, 0, stream>>>(Ah, Al, Wblk + 1 * 32768, nullptr, fd);
  gc_agg_kernel<<<NN, 128, 0, stream>>>(fd, rowoff, indeg, csr_src, b_gc2, nullptr,
                                        h0, Ah, Al);

  // GATv2 x3
  for (int i = 0; i < 3; ++i) {
    gemm_mfma<<<GEMM_GRID, 256, 0, stream>>>(Ah, Al, Wblk + (2 + i) * 32768, b_src + i * HIDD, fs);
    gemm_mfma<<<GEMM_GRID, 256, 0, stream>>>(Ah, Al, Wblk + (5 + i) * 32768, b_dst + i * HIDD, fd);
    bool last = (i == 2);
    gat_node_kernel<<<NN, 128, 0, stream>>>(fs, fd, attn + i * HEADS * DHH,
                                            rowoff, indeg, csr_src, h0,
                                            last ? nullptr : Ah, last ? nullptr : Al);
  }

  // pooling + MLP
  hipMemsetAsync(hg, 0, GG * HIDD * sizeof(float), stream);
  pool_kernel<<<GG * 8, 128, 0, stream>>>(h0, n2g, (unsigned*)hg);
  mlp_kernel<<<GG, 128, 0, stream>>>(hg, Wc1, bc1, Wc2, bc2, Wc3, bc3, (float*)d_out);
}

// Round 6
// 583.866 us; speedup vs baseline: 8.5855x; 1.0169x over previous
//
#include <hip/hip_runtime.h>
#include <hip/hip_bf16.h>

#define NN 50000
#define EE 500000
#define GG 64
#define HIDD 128
#define HEADS 8
#define DHH 16
#define NBLK ((NN + 255) / 256)   // 196
#define RTILES 3128               // ceil(50000/16) rowtiles of 16
#define GEMM_GRID 391             // ceil(50000/128)

typedef __bf16 bf16x8 __attribute__((ext_vector_type(8)));
typedef float f32x4 __attribute__((ext_vector_type(4)));

// 8-lane sum reduce, pure DPP: quad xor1, quad xor2, cross-quad (row_half_mirror = l^7).
__device__ inline float rowsum8(float y) {
  int t;
  t = __builtin_amdgcn_mov_dpp(__float_as_int(y), 0xB1, 0xF, 0xF, true);  y += __int_as_float(t); // quad_perm [1,0,3,2]
  t = __builtin_amdgcn_mov_dpp(__float_as_int(y), 0x4E, 0xF, 0xF, true);  y += __int_as_float(t); // quad_perm [2,3,0,1]
  t = __builtin_amdgcn_mov_dpp(__float_as_int(y), 0x141, 0xF, 0xF, true); y += __int_as_float(t); // row_half_mirror
  return y;
}

// blocked bf16 fragment offset for element (row, 8-col-group kc)
__device__ inline int frag_off(int row, int kc) {
  return (row >> 4) * 2048 + (kc >> 2) * 512 + ((row & 15) + (kc & 3) * 16) * 8;
}

// ---------------- degree ----------------
__global__ void deg_kernel(const int* __restrict__ src, const int* __restrict__ dst,
                           int* __restrict__ outdeg, int* __restrict__ indeg) {
  int i = blockIdx.x * blockDim.x + threadIdx.x;
  int stride = gridDim.x * blockDim.x;
  for (; i < EE; i += stride) {
    atomicAdd(&outdeg[src[i]], 1);
    atomicAdd(&indeg[dst[i]], 1);
  }
}

__global__ void norm_kernel(const int* __restrict__ outdeg, float* __restrict__ ns) {
  int i = blockIdx.x * blockDim.x + threadIdx.x;
  if (i < NN) ns[i] = rsqrtf((float)max(outdeg[i], 1));
}

// ---------------- hierarchical exclusive scan ----------------
__global__ __launch_bounds__(256) void scan1_kernel(const int* __restrict__ deg,
                                                    int* __restrict__ excl,
                                                    int* __restrict__ bsum) {
  __shared__ int buf[256];
  int t = threadIdx.x;
  int idx = blockIdx.x * 256 + t;
  int v = (idx < NN) ? deg[idx] : 0;
  buf[t] = v;
  __syncthreads();
#pragma unroll
  for (int off = 1; off < 256; off <<= 1) {
    int tmp = (t >= off) ? buf[t - off] : 0;
    __syncthreads();
    buf[t] += tmp;
    __syncthreads();
  }
  if (idx < NN) excl[idx] = buf[t] - v;
  if (t == 255) bsum[blockIdx.x] = buf[255];
}

__global__ __launch_bounds__(256) void scan2_kernel(int* __restrict__ bsum) {
  __shared__ int buf[256];
  int t = threadIdx.x;
  int v = (t < NBLK) ? bsum[t] : 0;
  buf[t] = v;
  __syncthreads();
#pragma unroll
  for (int off = 1; off < 256; off <<= 1) {
    int tmp = (t >= off) ? buf[t - off] : 0;
    __syncthreads();
    buf[t] += tmp;
    __syncthreads();
  }
  if (t < NBLK) bsum[t] = buf[t] - v;
}

__global__ __launch_bounds__(256) void scan3_kernel(int* __restrict__ excl,
                                                    const int* __restrict__ bsum,
                                                    int* __restrict__ cursor) {
  int idx = blockIdx.x * 256 + threadIdx.x;
  if (idx < NN) {
    int v = excl[idx] + bsum[blockIdx.x];
    excl[idx] = v;
    cursor[idx] = v;
  }
}

__global__ void bin_kernel(const int* __restrict__ src, const int* __restrict__ dst,
                           int* __restrict__ cursor, int* __restrict__ csr_src) {
  int i = blockIdx.x * blockDim.x + threadIdx.x;
  int stride = gridDim.x * blockDim.x;
  for (; i < EE; i += stride) {
    int pos = atomicAdd(&cursor[dst[i]], 1);
    csr_src[pos] = src[i];
  }
}

// ---------------- bf16 hi/lo weight split (transposed, k-blocked, pre-swizzled) ----------------
__global__ __launch_bounds__(256) void split_w_kernel(
    const float* __restrict__ W_gc1, const float* __restrict__ W_gc2,
    const float* __restrict__ W_src, const float* __restrict__ W_dst,
    __bf16* __restrict__ Wblk)
{
  int tid = blockIdx.x * 256 + threadIdx.x;   // 8 * 16384
  int m = tid >> 14;
  int kn = tid & 16383;
  int k = kn >> 7, n = kn & 127;
  const float* Wm = (m == 0) ? W_gc1 : (m == 1) ? W_gc2
                   : (m < 5) ? (W_src + (m - 2) * 16384) : (W_dst + (m - 5) * 16384);
  float v = Wm[kn];
  __bf16 h = (__bf16)v;
  __bf16 l = (__bf16)(v - (float)h);
  int ks = k >> 5;
  int L = n * 32 + ((k >> 3) & 3) * 8 + (k & 7);
  int swz = L ^ ((n & 7) << 3);
  __bf16* dstp = Wblk + m * 32768 + ks * 8192;
  dstp[swz] = h;
  dstp[4096 + swz] = l;
}

// ---------------- bf16 hi/lo input split (feature only) ----------------
__global__ __launch_bounds__(256) void split_h_kernel(
    const float* __restrict__ X, const float* __restrict__ scale,
    __bf16* __restrict__ Ah, __bf16* __restrict__ Al)
{
  int tid = blockIdx.x * 256 + threadIdx.x;   // RTILES*16*16
  int row = tid >> 4, kc = tid & 15;
  float v[8];
  if (row < NN) {
    const float4* p = (const float4*)(X + row * 128 + kc * 8);
    float4 a = p[0], b = p[1];
    float s = scale ? scale[row] : 1.f;
    v[0] = a.x * s; v[1] = a.y * s; v[2] = a.z * s; v[3] = a.w * s;
    v[4] = b.x * s; v[5] = b.y * s; v[6] = b.z * s; v[7] = b.w * s;
  } else {
#pragma unroll
    for (int i = 0; i < 8; ++i) v[i] = 0.f;
  }
  bf16x8 hi, lo;
#pragma unroll
  for (int i = 0; i < 8; ++i) {
    __bf16 h = (__bf16)v[i];
    hi[i] = h;
    lo[i] = (__bf16)(v[i] - (float)h);
  }
  int off = frag_off(row, kc);
  *(bf16x8*)(Ah + off) = hi;
  *(bf16x8*)(Al + off) = lo;
}

// ---------------- bf16x3 MFMA GEMM ----------------
__global__ __launch_bounds__(256) void gemm_mfma(
    const __bf16* __restrict__ Ah, const __bf16* __restrict__ Al,
    const __bf16* __restrict__ Wmat, const float* __restrict__ bias,
    float* __restrict__ out)
{
  __shared__ __bf16 wt[8192];
  int tid = threadIdx.x;
  int wid = tid >> 6, lane = tid & 63;
  int wr = wid >> 1, wc = wid & 1;
  int l15 = lane & 15, l4 = lane >> 4;
  f32x4 acc[4][4];
#pragma unroll
  for (int a = 0; a < 4; ++a)
#pragma unroll
    for (int b = 0; b < 4; ++b) acc[a][b] = (f32x4){0.f, 0.f, 0.f, 0.f};
  int rowtile0 = blockIdx.x * 8 + wr * 4;

  for (int ks = 0; ks < 4; ++ks) {
    {
      const bf16x8* g = (const bf16x8*)(Wmat + ks * 8192);
      bf16x8* l = (bf16x8*)wt;
      l[tid]       = g[tid];
      l[tid + 256] = g[tid + 256];
      l[tid + 512] = g[tid + 512];
      l[tid + 768] = g[tid + 768];
    }
    bf16x8 ah[4], al[4];
#pragma unroll
    for (int rt = 0; rt < 4; ++rt) {
      int off = (rowtile0 + rt) * 2048 + ks * 512 + lane * 8;
      ah[rt] = *(const bf16x8*)(Ah + off);
      al[rt] = *(const bf16x8*)(Al + off);
    }
    __syncthreads();
#pragma unroll
    for (int ct = 0; ct < 4; ++ct) {
      int n = wc * 64 + ct * 16 + l15;
      int ei = (n * 32 + l4 * 8) ^ ((n & 7) << 3);
      bf16x8 bh = *(const bf16x8*)(wt + ei);
      bf16x8 bl = *(const bf16x8*)(wt + 4096 + ei);
#pragma unroll
      for (int rt = 0; rt < 4; ++rt) {
        acc[rt][ct] = __builtin_amdgcn_mfma_f32_16x16x32_bf16(ah[rt], bh, acc[rt][ct], 0, 0, 0);
        acc[rt][ct] = __builtin_amdgcn_mfma_f32_16x16x32_bf16(ah[rt], bl, acc[rt][ct], 0, 0, 0);
        acc[rt][ct] = __builtin_amdgcn_mfma_f32_16x16x32_bf16(al[rt], bh, acc[rt][ct], 0, 0, 0);
      }
    }
    __syncthreads();
  }
  int rowbase = blockIdx.x * 128 + wr * 64;
#pragma unroll
  for (int ct = 0; ct < 4; ++ct) {
    int col = wc * 64 + ct * 16 + l15;
    float b = bias ? bias[col] : 0.f;
#pragma unroll
    for (int rt = 0; rt < 4; ++rt) {
#pragma unroll
      for (int r = 0; r < 4; ++r) {
        int row = rowbase + rt * 16 + l4 * 4 + r;
        if (row < NN) out[row * 128 + col] = acc[rt][ct][r] + b;
      }
    }
  }
}

// ---------------- GraphConv aggregation: 64 thr/node, float2, x4 unroll, fused split ----------------
__global__ __launch_bounds__(64) void gc_agg_kernel(
    const float2* __restrict__ m2, const int* __restrict__ rowoff,
    const int* __restrict__ indeg, const int* __restrict__ csr_src,
    const float2* __restrict__ bias2, const float* __restrict__ nsrow,
    float2* __restrict__ out2,        // null = skip fp32 write
    __bf16* __restrict__ Ah, __bf16* __restrict__ Al)   // null = skip split
{
  __shared__ float buf[128];
  int d = blockIdx.x, c = threadIdx.x;
  int ro = rowoff[d], dg = indeg[d];
  float2 a0 = {0.f, 0.f}, a1 = {0.f, 0.f}, a2 = {0.f, 0.f}, a3 = {0.f, 0.f};
  int j = 0;
  for (; j + 4 <= dg; j += 4) {
    int s0 = csr_src[ro + j], s1 = csr_src[ro + j + 1];
    int s2 = csr_src[ro + j + 2], s3 = csr_src[ro + j + 3];
    float2 v0 = m2[s0 * 64 + c], v1 = m2[s1 * 64 + c];
    float2 v2 = m2[s2 * 64 + c], v3 = m2[s3 * 64 + c];
    a0.x += v0.x; a0.y += v0.y; a1.x += v1.x; a1.y += v1.y;
    a2.x += v2.x; a2.y += v2.y; a3.x += v3.x; a3.y += v3.y;
  }
  for (; j < dg; ++j) {
    float2 v = m2[csr_src[ro + j] * 64 + c];
    a0.x += v.x; a0.y += v.y;
  }
  float accx = (a0.x + a1.x) + (a2.x + a3.x);
  float accy = (a0.y + a1.y) + (a2.y + a3.y);
  float ndv = rsqrtf((float)max(dg, 1));
  float2 b = bias2[c];
  float vx = fmaxf(accx * ndv + b.x, 0.f);
  float vy = fmaxf(accy * ndv + b.y, 0.f);
  if (out2) out2[d * 64 + c] = make_float2(vx, vy);
  if (Ah) {
    float s = nsrow ? nsrow[d] : 1.f;
    ((float2*)buf)[c] = make_float2(vx * s, vy * s);
    __syncthreads();
    if (c < 32) {
      int kc = c & 15;
      int off = frag_off(d, kc);
      bf16x8 pk;
      if (c < 16) {
#pragma unroll
        for (int i = 0; i < 8; ++i) pk[i] = (__bf16)buf[kc * 8 + i];
        *(bf16x8*)(Ah + off) = pk;
      } else {
#pragma unroll
        for (int i = 0; i < 8; ++i) {
          float x = buf[kc * 8 + i];
          __bf16 hh = (__bf16)x;
          pk[i] = (__bf16)(x - (float)hh);
        }
        *(bf16x8*)(Al + off) = pk;
      }
    }
  }
}

// ---------------- Fused GATv2: 64 thr/node, float2, DPP reduce, 2-way online softmax ----------------
__global__ __launch_bounds__(64) void gat_node_kernel(
    const float2* __restrict__ fs2, const float2* __restrict__ fd2,
    const float* __restrict__ attn,
    const int* __restrict__ rowoff, const int* __restrict__ indeg,
    const int* __restrict__ csr_src,
    float2* __restrict__ h2,          // in/out
    __bf16* __restrict__ Ah, __bf16* __restrict__ Al)   // null = skip split
{
  __shared__ float buf[128];
  int d = blockIdx.x, c = threadIdx.x;
  int ro = rowoff[d], dg = indeg[d];
  float2 fdp = fd2[d * 64 + c];
  float2 ap = ((const float2*)attn)[c];
  float mA = -INFINITY, sA = 0.f; float2 aA = {0.f, 0.f};
  float mB = -INFINITY, sB = 0.f; float2 aB = {0.f, 0.f};
  int j = 0;
  for (; j + 2 <= dg; j += 2) {
    int s0 = csr_src[ro + j], s1 = csr_src[ro + j + 1];
    float2 f0 = fs2[s0 * 64 + c], f1 = fs2[s1 * 64 + c];
    float x0 = f0.x + fdp.x; x0 = fmaxf(x0, 0.f) + 0.2f * fminf(x0, 0.f);
    float z0 = f0.y + fdp.y; z0 = fmaxf(z0, 0.f) + 0.2f * fminf(z0, 0.f);
    float x1 = f1.x + fdp.x; x1 = fmaxf(x1, 0.f) + 0.2f * fminf(x1, 0.f);
    float z1 = f1.y + fdp.y; z1 = fmaxf(z1, 0.f) + 0.2f * fminf(z1, 0.f);
    float y0 = rowsum8(ap.x * x0 + ap.y * z0);
    float y1 = rowsum8(ap.x * x1 + ap.y * z1);
    float nm = fmaxf(mA, y0);
    float sc = __expf(mA - nm), p = __expf(y0 - nm);
    sA = sA * sc + p; aA.x = aA.x * sc + p * f0.x; aA.y = aA.y * sc + p * f0.y; mA = nm;
    nm = fmaxf(mB, y1);
    sc = __expf(mB - nm); p = __expf(y1 - nm);
    sB = sB * sc + p; aB.x = aB.x * sc + p * f1.x; aB.y = aB.y * sc + p * f1.y; mB = nm;
  }
  if (j < dg) {
    int s0 = csr_src[ro + j];
    float2 f0 = fs2[s0 * 64 + c];
    float x0 = f0.x + fdp.x; x0 = fmaxf(x0, 0.f) + 0.2f * fminf(x0, 0.f);
    float z0 = f0.y + fdp.y; z0 = fmaxf(z0, 0.f) + 0.2f * fminf(z0, 0.f);
    float y0 = rowsum8(ap.x * x0 + ap.y * z0);
    float nm = fmaxf(mA, y0);
    float sc = __expf(mA - nm), p = __expf(y0 - nm);
    sA = sA * sc + p; aA.x = aA.x * sc + p * f0.x; aA.y = aA.y * sc + p * f0.y; mA = nm;
  }
  float ox = 0.f, oy = 0.f;
  if (dg > 0) {
    float M = fmaxf(mA, mB);
    float eA = __expf(mA - M), eB = __expf(mB - M);   // exp(-inf)=0 handles dg==1
    float inv = 1.f / (sA * eA + sB * eB);
    ox = (aA.x * eA + aB.x * eB) * inv;
    oy = (aA.y * eA + aB.y * eB) * inv;
  }
  float2 hv = h2[d * 64 + c];
  float vx = fmaxf(ox + hv.x, 0.f);
  float vy = fmaxf(oy + hv.y, 0.f);
  h2[d * 64 + c] = make_float2(vx, vy);
  if (Ah) {
    ((float2*)buf)[c] = make_float2(vx, vy);
    __syncthreads();
    if (c < 32) {
      int kc = c & 15;
      int off = frag_off(d, kc);
      bf16x8 pk;
      if (c < 16) {
#pragma unroll
        for (int i = 0; i < 8; ++i) pk[i] = (__bf16)buf[kc * 8 + i];
        *(bf16x8*)(Ah + off) = pk;
      } else {
#pragma unroll
        for (int i = 0; i < 8; ++i) {
          float x = buf[kc * 8 + i];
          __bf16 hh = (__bf16)x;
          pk[i] = (__bf16)(x - (float)hh);
        }
        *(bf16x8*)(Al + off) = pk;
      }
    }
  }
}

// ---------------- pooling (n2g sorted: per-graph range + few atomics) ----------------
__global__ __launch_bounds__(128) void pool_kernel(const float* __restrict__ h,
                                                   const int* __restrict__ n2g,
                                                   unsigned* __restrict__ hg)
{
  int g = blockIdx.x >> 3, chunk = blockIdx.x & 7, c = threadIdx.x;
  int lo = 0, hi = NN;
  while (lo < hi) { int mid = (lo + hi) >> 1; if (n2g[mid] < g) lo = mid + 1; else hi = mid; }
  int start = lo;
  hi = NN;
  while (lo < hi) { int mid = (lo + hi) >> 1; if (n2g[mid] < g + 1) lo = mid + 1; else hi = mid; }
  int end = lo;
  int len = end - start;
  int s = start + (int)(((long long)len * chunk) >> 3);
  int e = start + (int)(((long long)len * (chunk + 1)) >> 3);
  float m = 0.f;
  for (int r = s; r < e; ++r) m = fmaxf(m, h[r * 128 + c]);
  atomicMax(&hg[g * 128 + c], __float_as_uint(m));
}

__global__ __launch_bounds__(128) void mlp_kernel(
    const float* __restrict__ hg,
    const float* __restrict__ Wc1, const float* __restrict__ bc1,
    const float* __restrict__ Wc2, const float* __restrict__ bc2,
    const float* __restrict__ Wc3, const float* __restrict__ bc3,
    float* __restrict__ out)
{
  __shared__ float x[128], z1[128], z2[64];
  int g = blockIdx.x, t = threadIdx.x;
  x[t] = hg[g * 128 + t];
  __syncthreads();
  float acc = bc1[t];
  for (int k = 0; k < 128; ++k) acc += x[k] * Wc1[k * 128 + t];
  z1[t] = fmaxf(acc, 0.f);
  __syncthreads();
  if (t < 64) {
    float a2 = bc2[t];
    for (int k = 0; k < 128; ++k) a2 += z1[k] * Wc2[k * 64 + t];
    z2[t] = fmaxf(a2, 0.f);
  }
  __syncthreads();
#pragma unroll
  for (int p = 0; p < 2; ++p) {
    int c = t + p * 128;
    float a3 = bc3[c];
    for (int k = 0; k < 64; ++k) a3 += z2[k] * Wc3[k * 256 + c];
    out[g * 256 + c] = a3;
  }
}

// ---------------- launch ----------------
extern "C" void kernel_launch(void* const* d_in, const int* in_sizes, int n_in,
                              void* d_out, int out_size, void* d_ws, size_t ws_size,
                              hipStream_t stream)
{
  const float* feature = (const float*)d_in[0];
  const float* W_gc1 = (const float*)d_in[1];
  const float* b_gc1 = (const float*)d_in[2];
  const float* W_gc2 = (const float*)d_in[3];
  const float* b_gc2 = (const float*)d_in[4];
  const float* W_src = (const float*)d_in[5];
  const float* b_src = (const float*)d_in[6];
  const float* W_dst = (const float*)d_in[7];
  const float* b_dst = (const float*)d_in[8];
  const float* attn  = (const float*)d_in[9];
  const float* Wc1 = (const float*)d_in[10];
  const float* bc1 = (const float*)d_in[11];
  const float* Wc2 = (const float*)d_in[12];
  const float* bc2 = (const float*)d_in[13];
  const float* Wc3 = (const float*)d_in[14];
  const float* bc3 = (const float*)d_in[15];
  const int* src = (const int*)d_in[16];
  const int* dst = (const int*)d_in[17];
  const int* n2g = (const int*)d_in[18];

  char* base = (char*)d_ws;
  int* indeg  = (int*)base;            base += NN * sizeof(int);
  int* outdeg = (int*)base;            base += NN * sizeof(int);
  int* rowoff = (int*)base;            base += NN * sizeof(int);
  int* cursor = (int*)base;            base += NN * sizeof(int);
  int* bsum   = (int*)base;            base += 256 * sizeof(int);
  int* csr_src = (int*)base;           base += EE * sizeof(int);
  float* ns = (float*)base;            base += NN * sizeof(float);
  float* h0 = (float*)base;            base += (size_t)NN * HIDD * sizeof(float);
  float* fs = (float*)base;            base += (size_t)NN * HIDD * sizeof(float);
  float* fd = (float*)base;            base += (size_t)NN * HIDD * sizeof(float);
  __bf16* Ah = (__bf16*)base;          base += (size_t)RTILES * 2048 * sizeof(__bf16);
  __bf16* Al = (__bf16*)base;          base += (size_t)RTILES * 2048 * sizeof(__bf16);
  __bf16* Wblk = (__bf16*)base;        base += (size_t)8 * 32768 * sizeof(__bf16);
  float* hg = (float*)base;            base += GG * HIDD * sizeof(float);

  // degrees, norms, CSR
  hipMemsetAsync(indeg, 0, 2 * NN * sizeof(int), stream);
  deg_kernel<<<2048, 256, 0, stream>>>(src, dst, outdeg, indeg);
  norm_kernel<<<NBLK, 256, 0, stream>>>(outdeg, ns);
  scan1_kernel<<<NBLK, 256, 0, stream>>>(indeg, rowoff, bsum);
  scan2_kernel<<<1, 256, 0, stream>>>(bsum);
  scan3_kernel<<<NBLK, 256, 0, stream>>>(rowoff, bsum, cursor);
  bin_kernel<<<2048, 256, 0, stream>>>(src, dst, cursor, csr_src);

  // weight split (all 8 matrices)
  split_w_kernel<<<512, 256, 0, stream>>>(W_gc1, W_gc2, W_src, W_dst, Wblk);

  const int split_grid = RTILES * 16 * 16 / 256;

  // GC1: split(feature*ns) -> gemm -> agg (writes only next split, scaled by ns)
  split_h_kernel<<<split_grid, 256, 0, stream>>>(feature, ns, Ah, Al);
  gemm_mfma<<<GEMM_GRID, 256, 0, stream>>>(Ah, Al, Wblk + 0 * 32768, nullptr, fd);
  gc_agg_kernel<<<NN, 64, 0, stream>>>((const float2*)fd, rowoff, indeg, csr_src,
                                       (const float2*)b_gc1, ns, nullptr, Ah, Al);
  // GC2: gemm -> agg (writes h0 + unscaled split for GAT1)
  gemm_mfma<<<GEMM_GRID, 256, 0, stream>>>(Ah, Al, Wblk + 1 * 32768, nullptr, fd);
  gc_agg_kernel<<<NN, 64, 0, stream>>>((const float2*)fd, rowoff, indeg, csr_src,
                                       (const float2*)b_gc2, nullptr, (float2*)h0, Ah, Al);

  // GATv2 x3
  for (int i = 0; i < 3; ++i) {
    gemm_mfma<<<GEMM_GRID, 256, 0, stream>>>(Ah, Al, Wblk + (2 + i) * 32768, b_src + i * HIDD, fs);
    gemm_mfma<<<GEMM_GRID, 256, 0, stream>>>(Ah, Al, Wblk + (5 + i) * 32768, b_dst + i * HIDD, fd);
    bool last = (i == 2);
    gat_node_kernel<<<NN, 64, 0, stream>>>((const float2*)fs, (const float2*)fd,
                                           attn + i * HEADS * DHH,
                                           rowoff, indeg, csr_src, (float2*)h0,
                                           last ? nullptr : Ah, last ? nullptr : Al);
  }

  // pooling + MLP
  hipMemsetAsync(hg, 0, GG * HIDD * sizeof(float), stream);
  pool_kernel<<<GG * 8, 128, 0, stream>>>(h0, n2g, (unsigned*)hg);
  mlp_kernel<<<GG, 128, 0, stream>>>(hg, Wc1, bc1, Wc2, bc2, Wc3, bc3, (float*)d_out);
}

// Round 7
// 559.847 us; speedup vs baseline: 8.9539x; 1.0429x over previous
//
#include <hip/hip_runtime.h>
#include <hip/hip_bf16.h>

#define NN 50000
#define EE 500000
#define GG 64
#define HIDD 128
#define HEADS 8
#define DHH 16
#define NBLK ((NN + 255) / 256)   // 196
#define RTILES 3128               // ceil(50000/16) rowtiles of 16
#define GEMM_GRID 391             // ceil(50000/128)

typedef __bf16 bf16x8 __attribute__((ext_vector_type(8)));
typedef float f32x4 __attribute__((ext_vector_type(4)));

// 8-lane sum reduce, pure DPP: quad xor1, quad xor2, cross-quad (row_half_mirror = l^7).
__device__ inline float rowsum8(float y) {
  int t;
  t = __builtin_amdgcn_mov_dpp(__float_as_int(y), 0xB1, 0xF, 0xF, true);  y += __int_as_float(t); // quad_perm [1,0,3,2]
  t = __builtin_amdgcn_mov_dpp(__float_as_int(y), 0x4E, 0xF, 0xF, true);  y += __int_as_float(t); // quad_perm [2,3,0,1]
  t = __builtin_amdgcn_mov_dpp(__float_as_int(y), 0x141, 0xF, 0xF, true); y += __int_as_float(t); // row_half_mirror
  return y;
}

// blocked bf16 fragment offset for element (row, 8-col-group kc)
__device__ inline int frag_off(int row, int kc) {
  return (row >> 4) * 2048 + (kc >> 2) * 512 + ((row & 15) + (kc & 3) * 16) * 8;
}

// ---------------- degree ----------------
__global__ void deg_kernel(const int* __restrict__ src, const int* __restrict__ dst,
                           int* __restrict__ outdeg, int* __restrict__ indeg) {
  int i = blockIdx.x * blockDim.x + threadIdx.x;
  int stride = gridDim.x * blockDim.x;
  for (; i < EE; i += stride) {
    atomicAdd(&outdeg[src[i]], 1);
    atomicAdd(&indeg[dst[i]], 1);
  }
}

__global__ void norm_kernel(const int* __restrict__ outdeg, float* __restrict__ ns) {
  int i = blockIdx.x * blockDim.x + threadIdx.x;
  if (i < NN) ns[i] = rsqrtf((float)max(outdeg[i], 1));
}

// ---------------- hierarchical exclusive scan ----------------
__global__ __launch_bounds__(256) void scan1_kernel(const int* __restrict__ deg,
                                                    int* __restrict__ excl,
                                                    int* __restrict__ bsum) {
  __shared__ int buf[256];
  int t = threadIdx.x;
  int idx = blockIdx.x * 256 + t;
  int v = (idx < NN) ? deg[idx] : 0;
  buf[t] = v;
  __syncthreads();
#pragma unroll
  for (int off = 1; off < 256; off <<= 1) {
    int tmp = (t >= off) ? buf[t - off] : 0;
    __syncthreads();
    buf[t] += tmp;
    __syncthreads();
  }
  if (idx < NN) excl[idx] = buf[t] - v;
  if (t == 255) bsum[blockIdx.x] = buf[255];
}

__global__ __launch_bounds__(256) void scan2_kernel(int* __restrict__ bsum) {
  __shared__ int buf[256];
  int t = threadIdx.x;
  int v = (t < NBLK) ? bsum[t] : 0;
  buf[t] = v;
  __syncthreads();
#pragma unroll
  for (int off = 1; off < 256; off <<= 1) {
    int tmp = (t >= off) ? buf[t - off] : 0;
    __syncthreads();
    buf[t] += tmp;
    __syncthreads();
  }
  if (t < NBLK) bsum[t] = buf[t] - v;
}

__global__ __launch_bounds__(256) void scan3_kernel(int* __restrict__ excl,
                                                    const int* __restrict__ bsum,
                                                    int* __restrict__ cursor) {
  int idx = blockIdx.x * 256 + threadIdx.x;
  if (idx < NN) {
    int v = excl[idx] + bsum[blockIdx.x];
    excl[idx] = v;
    cursor[idx] = v;
  }
}

__global__ void bin_kernel(const int* __restrict__ src, const int* __restrict__ dst,
                           int* __restrict__ cursor, int* __restrict__ csr_src) {
  int i = blockIdx.x * blockDim.x + threadIdx.x;
  int stride = gridDim.x * blockDim.x;
  for (; i < EE; i += stride) {
    int pos = atomicAdd(&cursor[dst[i]], 1);
    csr_src[pos] = src[i];
  }
}

// ---------------- bf16 hi/lo weight split (transposed, k-blocked, pre-swizzled) ----------------
__global__ __launch_bounds__(256) void split_w_kernel(
    const float* __restrict__ W_gc1, const float* __restrict__ W_gc2,
    const float* __restrict__ W_src, const float* __restrict__ W_dst,
    __bf16* __restrict__ Wblk)
{
  int tid = blockIdx.x * 256 + threadIdx.x;   // 8 * 16384
  int m = tid >> 14;
  int kn = tid & 16383;
  int k = kn >> 7, n = kn & 127;
  const float* Wm = (m == 0) ? W_gc1 : (m == 1) ? W_gc2
                   : (m < 5) ? (W_src + (m - 2) * 16384) : (W_dst + (m - 5) * 16384);
  float v = Wm[kn];
  __bf16 h = (__bf16)v;
  __bf16 l = (__bf16)(v - (float)h);
  int ks = k >> 5;
  int L = n * 32 + ((k >> 3) & 3) * 8 + (k & 7);
  int swz = L ^ ((n & 7) << 3);
  __bf16* dstp = Wblk + m * 32768 + ks * 8192;
  dstp[swz] = h;
  dstp[4096 + swz] = l;
}

// ---------------- bf16 hi/lo input split (feature only) ----------------
__global__ __launch_bounds__(256) void split_h_kernel(
    const float* __restrict__ X, const float* __restrict__ scale,
    __bf16* __restrict__ Ah, __bf16* __restrict__ Al)
{
  int tid = blockIdx.x * 256 + threadIdx.x;   // RTILES*16*16
  int row = tid >> 4, kc = tid & 15;
  float v[8];
  if (row < NN) {
    const float4* p = (const float4*)(X + row * 128 + kc * 8);
    float4 a = p[0], b = p[1];
    float s = scale ? scale[row] : 1.f;
    v[0] = a.x * s; v[1] = a.y * s; v[2] = a.z * s; v[3] = a.w * s;
    v[4] = b.x * s; v[5] = b.y * s; v[6] = b.z * s; v[7] = b.w * s;
  } else {
#pragma unroll
    for (int i = 0; i < 8; ++i) v[i] = 0.f;
  }
  bf16x8 hi, lo;
#pragma unroll
  for (int i = 0; i < 8; ++i) {
    __bf16 h = (__bf16)v[i];
    hi[i] = h;
    lo[i] = (__bf16)(v[i] - (float)h);
  }
  int off = frag_off(row, kc);
  *(bf16x8*)(Ah + off) = hi;
  *(bf16x8*)(Al + off) = lo;
}

// ---------------- bf16x3 MFMA GEMM (fp32 or bf16 output) ----------------
__global__ __launch_bounds__(256) void gemm_mfma(
    const __bf16* __restrict__ Ah, const __bf16* __restrict__ Al,
    const __bf16* __restrict__ Wmat, const float* __restrict__ bias,
    float* __restrict__ out,          // may be null
    __bf16* __restrict__ outb)        // may be null
{
  __shared__ __bf16 wt[8192];
  int tid = threadIdx.x;
  int wid = tid >> 6, lane = tid & 63;
  int wr = wid >> 1, wc = wid & 1;
  int l15 = lane & 15, l4 = lane >> 4;
  f32x4 acc[4][4];
#pragma unroll
  for (int a = 0; a < 4; ++a)
#pragma unroll
    for (int b = 0; b < 4; ++b) acc[a][b] = (f32x4){0.f, 0.f, 0.f, 0.f};
  int rowtile0 = blockIdx.x * 8 + wr * 4;

  for (int ks = 0; ks < 4; ++ks) {
    {
      const bf16x8* g = (const bf16x8*)(Wmat + ks * 8192);
      bf16x8* l = (bf16x8*)wt;
      l[tid]       = g[tid];
      l[tid + 256] = g[tid + 256];
      l[tid + 512] = g[tid + 512];
      l[tid + 768] = g[tid + 768];
    }
    bf16x8 ah[4], al[4];
#pragma unroll
    for (int rt = 0; rt < 4; ++rt) {
      int off = (rowtile0 + rt) * 2048 + ks * 512 + lane * 8;
      ah[rt] = *(const bf16x8*)(Ah + off);
      al[rt] = *(const bf16x8*)(Al + off);
    }
    __syncthreads();
#pragma unroll
    for (int ct = 0; ct < 4; ++ct) {
      int n = wc * 64 + ct * 16 + l15;
      int ei = (n * 32 + l4 * 8) ^ ((n & 7) << 3);
      bf16x8 bh = *(const bf16x8*)(wt + ei);
      bf16x8 bl = *(const bf16x8*)(wt + 4096 + ei);
#pragma unroll
      for (int rt = 0; rt < 4; ++rt) {
        acc[rt][ct] = __builtin_amdgcn_mfma_f32_16x16x32_bf16(ah[rt], bh, acc[rt][ct], 0, 0, 0);
        acc[rt][ct] = __builtin_amdgcn_mfma_f32_16x16x32_bf16(ah[rt], bl, acc[rt][ct], 0, 0, 0);
        acc[rt][ct] = __builtin_amdgcn_mfma_f32_16x16x32_bf16(al[rt], bh, acc[rt][ct], 0, 0, 0);
      }
    }
    __syncthreads();
  }
  int rowbase = blockIdx.x * 128 + wr * 64;
#pragma unroll
  for (int ct = 0; ct < 4; ++ct) {
    int col = wc * 64 + ct * 16 + l15;
    float b = bias ? bias[col] : 0.f;
#pragma unroll
    for (int rt = 0; rt < 4; ++rt) {
#pragma unroll
      for (int r = 0; r < 4; ++r) {
        int row = rowbase + rt * 16 + l4 * 4 + r;
        if (row < NN) {
          float v = acc[rt][ct][r] + b;
          if (out)  out[row * 128 + col] = v;
          if (outb) outb[row * 128 + col] = (__bf16)v;
        }
      }
    }
  }
}

// ---------------- GraphConv aggregation: 64 thr/node, float2, x4 unroll, fused split ----------------
__global__ __launch_bounds__(64) void gc_agg_kernel(
    const float2* __restrict__ m2, const int* __restrict__ rowoff,
    const int* __restrict__ indeg, const int* __restrict__ csr_src,
    const float2* __restrict__ bias2, const float* __restrict__ nsrow,
    float2* __restrict__ out2,        // null = skip fp32 write
    __bf16* __restrict__ Ah, __bf16* __restrict__ Al)   // null = skip split
{
  __shared__ float buf[128];
  int d = blockIdx.x, c = threadIdx.x;
  int ro = rowoff[d], dg = indeg[d];
  float2 a0 = {0.f, 0.f}, a1 = {0.f, 0.f}, a2 = {0.f, 0.f}, a3 = {0.f, 0.f};
  int j = 0;
  for (; j + 4 <= dg; j += 4) {
    int s0 = csr_src[ro + j], s1 = csr_src[ro + j + 1];
    int s2 = csr_src[ro + j + 2], s3 = csr_src[ro + j + 3];
    float2 v0 = m2[s0 * 64 + c], v1 = m2[s1 * 64 + c];
    float2 v2 = m2[s2 * 64 + c], v3 = m2[s3 * 64 + c];
    a0.x += v0.x; a0.y += v0.y; a1.x += v1.x; a1.y += v1.y;
    a2.x += v2.x; a2.y += v2.y; a3.x += v3.x; a3.y += v3.y;
  }
  for (; j < dg; ++j) {
    float2 v = m2[csr_src[ro + j] * 64 + c];
    a0.x += v.x; a0.y += v.y;
  }
  float accx = (a0.x + a1.x) + (a2.x + a3.x);
  float accy = (a0.y + a1.y) + (a2.y + a3.y);
  float ndv = rsqrtf((float)max(dg, 1));
  float2 b = bias2[c];
  float vx = fmaxf(accx * ndv + b.x, 0.f);
  float vy = fmaxf(accy * ndv + b.y, 0.f);
  if (out2) out2[d * 64 + c] = make_float2(vx, vy);
  if (Ah) {
    float s = nsrow ? nsrow[d] : 1.f;
    ((float2*)buf)[c] = make_float2(vx * s, vy * s);
    __syncthreads();
    if (c < 32) {
      int kc = c & 15;
      int off = frag_off(d, kc);
      bf16x8 pk;
      if (c < 16) {
#pragma unroll
        for (int i = 0; i < 8; ++i) pk[i] = (__bf16)buf[kc * 8 + i];
        *(bf16x8*)(Ah + off) = pk;
      } else {
#pragma unroll
        for (int i = 0; i < 8; ++i) {
          float x = buf[kc * 8 + i];
          __bf16 hh = (__bf16)x;
          pk[i] = (__bf16)(x - (float)hh);
        }
        *(bf16x8*)(Al + off) = pk;
      }
    }
  }
}

// ---------------- Fused GATv2: bf16 fs gather, DPP reduce, 2-way online softmax ----------------
__global__ __launch_bounds__(64) void gat_node_kernel(
    const __bf16* __restrict__ fsb,   // [N][128] bf16
    const float2* __restrict__ fd2,
    const float* __restrict__ attn,
    const int* __restrict__ rowoff, const int* __restrict__ indeg,
    const int* __restrict__ csr_src,
    float2* __restrict__ h2,          // in/out
    __bf16* __restrict__ Ah, __bf16* __restrict__ Al)   // null = skip split
{
  __shared__ float buf[128];
  int d = blockIdx.x, c = threadIdx.x;
  int ro = rowoff[d], dg = indeg[d];
  float2 fdp = fd2[d * 64 + c];
  float2 ap = ((const float2*)attn)[c];
  float mA = -INFINITY, sA = 0.f; float2 aA = {0.f, 0.f};
  float mB = -INFINITY, sB = 0.f; float2 aB = {0.f, 0.f};
  int j = 0;
  for (; j + 2 <= dg; j += 2) {
    int s0 = csr_src[ro + j], s1 = csr_src[ro + j + 1];
    unsigned u0 = *(const unsigned*)(fsb + s0 * 128 + 2 * c);
    unsigned u1 = *(const unsigned*)(fsb + s1 * 128 + 2 * c);
    float2 f0 = make_float2(__uint_as_float(u0 << 16), __uint_as_float(u0 & 0xFFFF0000u));
    float2 f1 = make_float2(__uint_as_float(u1 << 16), __uint_as_float(u1 & 0xFFFF0000u));
    float x0 = f0.x + fdp.x; x0 = fmaxf(x0, 0.f) + 0.2f * fminf(x0, 0.f);
    float z0 = f0.y + fdp.y; z0 = fmaxf(z0, 0.f) + 0.2f * fminf(z0, 0.f);
    float x1 = f1.x + fdp.x; x1 = fmaxf(x1, 0.f) + 0.2f * fminf(x1, 0.f);
    float z1 = f1.y + fdp.y; z1 = fmaxf(z1, 0.f) + 0.2f * fminf(z1, 0.f);
    float y0 = rowsum8(ap.x * x0 + ap.y * z0);
    float y1 = rowsum8(ap.x * x1 + ap.y * z1);
    float nm = fmaxf(mA, y0);
    float sc = __expf(mA - nm), p = __expf(y0 - nm);
    sA = sA * sc + p; aA.x = aA.x * sc + p * f0.x; aA.y = aA.y * sc + p * f0.y; mA = nm;
    nm = fmaxf(mB, y1);
    sc = __expf(mB - nm); p = __expf(y1 - nm);
    sB = sB * sc + p; aB.x = aB.x * sc + p * f1.x; aB.y = aB.y * sc + p * f1.y; mB = nm;
  }
  if (j < dg) {
    int s0 = csr_src[ro + j];
    unsigned u0 = *(const unsigned*)(fsb + s0 * 128 + 2 * c);
    float2 f0 = make_float2(__uint_as_float(u0 << 16), __uint_as_float(u0 & 0xFFFF0000u));
    float x0 = f0.x + fdp.x; x0 = fmaxf(x0, 0.f) + 0.2f * fminf(x0, 0.f);
    float z0 = f0.y + fdp.y; z0 = fmaxf(z0, 0.f) + 0.2f * fminf(z0, 0.f);
    float y0 = rowsum8(ap.x * x0 + ap.y * z0);
    float nm = fmaxf(mA, y0);
    float sc = __expf(mA - nm), p = __expf(y0 - nm);
    sA = sA * sc + p; aA.x = aA.x * sc + p * f0.x; aA.y = aA.y * sc + p * f0.y; mA = nm;
  }
  float ox = 0.f, oy = 0.f;
  if (dg > 0) {
    float M = fmaxf(mA, mB);
    float eA = __expf(mA - M), eB = __expf(mB - M);   // exp(-inf)=0 handles dg==1
    float inv = 1.f / (sA * eA + sB * eB);
    ox = (aA.x * eA + aB.x * eB) * inv;
    oy = (aA.y * eA + aB.y * eB) * inv;
  }
  float2 hv = h2[d * 64 + c];
  float vx = fmaxf(ox + hv.x, 0.f);
  float vy = fmaxf(oy + hv.y, 0.f);
  h2[d * 64 + c] = make_float2(vx, vy);
  if (Ah) {
    ((float2*)buf)[c] = make_float2(vx, vy);
    __syncthreads();
    if (c < 32) {
      int kc = c & 15;
      int off = frag_off(d, kc);
      bf16x8 pk;
      if (c < 16) {
#pragma unroll
        for (int i = 0; i < 8; ++i) pk[i] = (__bf16)buf[kc * 8 + i];
        *(bf16x8*)(Ah + off) = pk;
      } else {
#pragma unroll
        for (int i = 0; i < 8; ++i) {
          float x = buf[kc * 8 + i];
          __bf16 hh = (__bf16)x;
          pk[i] = (__bf16)(x - (float)hh);
        }
        *(bf16x8*)(Al + off) = pk;
      }
    }
  }
}

// ---------------- pooling (n2g sorted: per-graph range + few atomics) ----------------
__global__ __launch_bounds__(128) void pool_kernel(const float* __restrict__ h,
                                                   const int* __restrict__ n2g,
                                                   unsigned* __restrict__ hg)
{
  int g = blockIdx.x >> 3, chunk = blockIdx.x & 7, c = threadIdx.x;
  int lo = 0, hi = NN;
  while (lo < hi) { int mid = (lo + hi) >> 1; if (n2g[mid] < g) lo = mid + 1; else hi = mid; }
  int start = lo;
  hi = NN;
  while (lo < hi) { int mid = (lo + hi) >> 1; if (n2g[mid] < g + 1) lo = mid + 1; else hi = mid; }
  int end = lo;
  int len = end - start;
  int s = start + (int)(((long long)len * chunk) >> 3);
  int e = start + (int)(((long long)len * (chunk + 1)) >> 3);
  float m = 0.f;
  for (int r = s; r < e; ++r) m = fmaxf(m, h[r * 128 + c]);
  atomicMax(&hg[g * 128 + c], __float_as_uint(m));
}

__global__ __launch_bounds__(128) void mlp_kernel(
    const float* __restrict__ hg,
    const float* __restrict__ Wc1, const float* __restrict__ bc1,
    const float* __restrict__ Wc2, const float* __restrict__ bc2,
    const float* __restrict__ Wc3, const float* __restrict__ bc3,
    float* __restrict__ out)
{
  __shared__ float x[128], z1[128], z2[64];
  int g = blockIdx.x, t = threadIdx.x;
  x[t] = hg[g * 128 + t];
  __syncthreads();
  float acc = bc1[t];
  for (int k = 0; k < 128; ++k) acc += x[k] * Wc1[k * 128 + t];
  z1[t] = fmaxf(acc, 0.f);
  __syncthreads();
  if (t < 64) {
    float a2 = bc2[t];
    for (int k = 0; k < 128; ++k) a2 += z1[k] * Wc2[k * 64 + t];
    z2[t] = fmaxf(a2, 0.f);
  }
  __syncthreads();
#pragma unroll
  for (int p = 0; p < 2; ++p) {
    int c = t + p * 128;
    float a3 = bc3[c];
    for (int k = 0; k < 64; ++k) a3 += z2[k] * Wc3[k * 256 + c];
    out[g * 256 + c] = a3;
  }
}

// ---------------- launch ----------------
extern "C" void kernel_launch(void* const* d_in, const int* in_sizes, int n_in,
                              void* d_out, int out_size, void* d_ws, size_t ws_size,
                              hipStream_t stream)
{
  const float* feature = (const float*)d_in[0];
  const float* W_gc1 = (const float*)d_in[1];
  const float* b_gc1 = (const float*)d_in[2];
  const float* W_gc2 = (const float*)d_in[3];
  const float* b_gc2 = (const float*)d_in[4];
  const float* W_src = (const float*)d_in[5];
  const float* b_src = (const float*)d_in[6];
  const float* W_dst = (const float*)d_in[7];
  const float* b_dst = (const float*)d_in[8];
  const float* attn  = (const float*)d_in[9];
  const float* Wc1 = (const float*)d_in[10];
  const float* bc1 = (const float*)d_in[11];
  const float* Wc2 = (const float*)d_in[12];
  const float* bc2 = (const float*)d_in[13];
  const float* Wc3 = (const float*)d_in[14];
  const float* bc3 = (const float*)d_in[15];
  const int* src = (const int*)d_in[16];
  const int* dst = (const int*)d_in[17];
  const int* n2g = (const int*)d_in[18];

  char* base = (char*)d_ws;
  int* indeg  = (int*)base;            base += NN * sizeof(int);
  int* outdeg = (int*)base;            base += NN * sizeof(int);
  int* rowoff = (int*)base;            base += NN * sizeof(int);
  int* cursor = (int*)base;            base += NN * sizeof(int);
  int* bsum   = (int*)base;            base += 256 * sizeof(int);
  int* csr_src = (int*)base;           base += EE * sizeof(int);
  float* ns = (float*)base;            base += NN * sizeof(float);
  float* h0 = (float*)base;            base += (size_t)NN * HIDD * sizeof(float);
  __bf16* fsb = (__bf16*)base;         base += (size_t)NN * HIDD * sizeof(__bf16);
  float* fd = (float*)base;            base += (size_t)NN * HIDD * sizeof(float);
  __bf16* Ah = (__bf16*)base;          base += (size_t)RTILES * 2048 * sizeof(__bf16);
  __bf16* Al = (__bf16*)base;          base += (size_t)RTILES * 2048 * sizeof(__bf16);
  __bf16* Wblk = (__bf16*)base;        base += (size_t)8 * 32768 * sizeof(__bf16);
  float* hg = (float*)base;            base += GG * HIDD * sizeof(float);

  // degrees, norms, CSR
  hipMemsetAsync(indeg, 0, 2 * NN * sizeof(int), stream);
  deg_kernel<<<2048, 256, 0, stream>>>(src, dst, outdeg, indeg);
  norm_kernel<<<NBLK, 256, 0, stream>>>(outdeg, ns);
  scan1_kernel<<<NBLK, 256, 0, stream>>>(indeg, rowoff, bsum);
  scan2_kernel<<<1, 256, 0, stream>>>(bsum);
  scan3_kernel<<<NBLK, 256, 0, stream>>>(rowoff, bsum, cursor);
  bin_kernel<<<2048, 256, 0, stream>>>(src, dst, cursor, csr_src);

  // weight split (all 8 matrices)
  split_w_kernel<<<512, 256, 0, stream>>>(W_gc1, W_gc2, W_src, W_dst, Wblk);

  const int split_grid = RTILES * 16 * 16 / 256;

  // GC1: split(feature*ns) -> gemm -> agg (writes only next split, scaled by ns)
  split_h_kernel<<<split_grid, 256, 0, stream>>>(feature, ns, Ah, Al);
  gemm_mfma<<<GEMM_GRID, 256, 0, stream>>>(Ah, Al, Wblk + 0 * 32768, nullptr, fd, nullptr);
  gc_agg_kernel<<<NN, 64, 0, stream>>>((const float2*)fd, rowoff, indeg, csr_src,
                                       (const float2*)b_gc1, ns, nullptr, Ah, Al);
  // GC2: gemm -> agg (writes h0 + unscaled split for GAT1)
  gemm_mfma<<<GEMM_GRID, 256, 0, stream>>>(Ah, Al, Wblk + 1 * 32768, nullptr, fd, nullptr);
  gc_agg_kernel<<<NN, 64, 0, stream>>>((const float2*)fd, rowoff, indeg, csr_src,
                                       (const float2*)b_gc2, nullptr, (float2*)h0, Ah, Al);

  // GATv2 x3: fs GEMM writes bf16 (halves gather bytes), fd stays fp32
  for (int i = 0; i < 3; ++i) {
    gemm_mfma<<<GEMM_GRID, 256, 0, stream>>>(Ah, Al, Wblk + (2 + i) * 32768, b_src + i * HIDD,
                                             nullptr, fsb);
    gemm_mfma<<<GEMM_GRID, 256, 0, stream>>>(Ah, Al, Wblk + (5 + i) * 32768, b_dst + i * HIDD,
                                             fd, nullptr);
    bool last = (i == 2);
    gat_node_kernel<<<NN, 64, 0, stream>>>(fsb, (const float2*)fd,
                                           attn + i * HEADS * DHH,
                                           rowoff, indeg, csr_src, (float2*)h0,
                                           last ? nullptr : Ah, last ? nullptr : Al);
  }

  // pooling + MLP
  hipMemsetAsync(hg, 0, GG * HIDD * sizeof(float), stream);
  pool_kernel<<<GG * 8, 128, 0, stream>>>(h0, n2g, (unsigned*)hg);
  mlp_kernel<<<GG, 128, 0, stream>>>(hg, Wc1, bc1, Wc2, bc2, Wc3, bc3, (float*)d_out);
}

// Round 8
// 505.171 us; speedup vs baseline: 9.9230x; 1.1082x over previous
//
#include <hip/hip_runtime.h>
#include <hip/hip_bf16.h>

#define NN 50000
#define EE 500000
#define GG 64
#define HIDD 128
#define HEADS 8
#define DHH 16
#define NBLK ((NN + 255) / 256)   // 196
#define RTILES 3128               // ceil(50000/16) rowtiles of 16
#define GEMM_GRID 391             // ceil(50000/128)

typedef __bf16 bf16x8 __attribute__((ext_vector_type(8)));
typedef float f32x4 __attribute__((ext_vector_type(4)));

// 8-lane sum reduce, pure DPP: quad xor1, quad xor2, cross-quad (row_half_mirror = l^7).
__device__ inline float rowsum8(float y) {
  int t;
  t = __builtin_amdgcn_mov_dpp(__float_as_int(y), 0xB1, 0xF, 0xF, true);  y += __int_as_float(t); // quad_perm [1,0,3,2]
  t = __builtin_amdgcn_mov_dpp(__float_as_int(y), 0x4E, 0xF, 0xF, true);  y += __int_as_float(t); // quad_perm [2,3,0,1]
  t = __builtin_amdgcn_mov_dpp(__float_as_int(y), 0x141, 0xF, 0xF, true); y += __int_as_float(t); // row_half_mirror
  return y;
}

__device__ inline float2 unpk2(unsigned u) {
  return make_float2(__uint_as_float(u << 16), __uint_as_float(u & 0xFFFF0000u));
}

// blocked bf16 fragment offset for element (row, 8-col-group kc)
__device__ inline int frag_off(int row, int kc) {
  return (row >> 4) * 2048 + (kc >> 2) * 512 + ((row & 15) + (kc & 3) * 16) * 8;
}

// ---------------- degree ----------------
__global__ void deg_kernel(const int* __restrict__ src, const int* __restrict__ dst,
                           int* __restrict__ outdeg, int* __restrict__ indeg) {
  int i = blockIdx.x * blockDim.x + threadIdx.x;
  int stride = gridDim.x * blockDim.x;
  for (; i < EE; i += stride) {
    atomicAdd(&outdeg[src[i]], 1);
    atomicAdd(&indeg[dst[i]], 1);
  }
}

__global__ void norm_kernel(const int* __restrict__ outdeg, float* __restrict__ ns) {
  int i = blockIdx.x * blockDim.x + threadIdx.x;
  if (i < NN) ns[i] = rsqrtf((float)max(outdeg[i], 1));
}

// ---------------- hierarchical exclusive scan ----------------
__global__ __launch_bounds__(256) void scan1_kernel(const int* __restrict__ deg,
                                                    int* __restrict__ excl,
                                                    int* __restrict__ bsum) {
  __shared__ int buf[256];
  int t = threadIdx.x;
  int idx = blockIdx.x * 256 + t;
  int v = (idx < NN) ? deg[idx] : 0;
  buf[t] = v;
  __syncthreads();
#pragma unroll
  for (int off = 1; off < 256; off <<= 1) {
    int tmp = (t >= off) ? buf[t - off] : 0;
    __syncthreads();
    buf[t] += tmp;
    __syncthreads();
  }
  if (idx < NN) excl[idx] = buf[t] - v;
  if (t == 255) bsum[blockIdx.x] = buf[255];
}

__global__ __launch_bounds__(256) void scan2_kernel(int* __restrict__ bsum) {
  __shared__ int buf[256];
  int t = threadIdx.x;
  int v = (t < NBLK) ? bsum[t] : 0;
  buf[t] = v;
  __syncthreads();
#pragma unroll
  for (int off = 1; off < 256; off <<= 1) {
    int tmp = (t >= off) ? buf[t - off] : 0;
    __syncthreads();
    buf[t] += tmp;
    __syncthreads();
  }
  if (t < NBLK) bsum[t] = buf[t] - v;
}

__global__ __launch_bounds__(256) void scan3_kernel(int* __restrict__ excl,
                                                    const int* __restrict__ bsum,
                                                    int* __restrict__ cursor) {
  int idx = blockIdx.x * 256 + threadIdx.x;
  if (idx < NN) {
    int v = excl[idx] + bsum[blockIdx.x];
    excl[idx] = v;
    cursor[idx] = v;
  }
}

__global__ void bin_kernel(const int* __restrict__ src, const int* __restrict__ dst,
                           int* __restrict__ cursor, int* __restrict__ csr_src) {
  int i = blockIdx.x * blockDim.x + threadIdx.x;
  int stride = gridDim.x * blockDim.x;
  for (; i < EE; i += stride) {
    int pos = atomicAdd(&cursor[dst[i]], 1);
    csr_src[pos] = src[i];
  }
}

// ---------------- bf16 hi/lo weight split (transposed, k-blocked, pre-swizzled) ----------------
__global__ __launch_bounds__(256) void split_w_kernel(
    const float* __restrict__ W_gc1, const float* __restrict__ W_gc2,
    const float* __restrict__ W_src, const float* __restrict__ W_dst,
    __bf16* __restrict__ Wblk)
{
  int tid = blockIdx.x * 256 + threadIdx.x;   // 8 * 16384
  int m = tid >> 14;
  int kn = tid & 16383;
  int k = kn >> 7, n = kn & 127;
  const float* Wm = (m == 0) ? W_gc1 : (m == 1) ? W_gc2
                   : (m < 5) ? (W_src + (m - 2) * 16384) : (W_dst + (m - 5) * 16384);
  float v = Wm[kn];
  __bf16 h = (__bf16)v;
  __bf16 l = (__bf16)(v - (float)h);
  int ks = k >> 5;
  int L = n * 32 + ((k >> 3) & 3) * 8 + (k & 7);
  int swz = L ^ ((n & 7) << 3);
  __bf16* dstp = Wblk + m * 32768 + ks * 8192;
  dstp[swz] = h;
  dstp[4096 + swz] = l;
}

// ---------------- bf16 hi/lo input split (feature only) ----------------
__global__ __launch_bounds__(256) void split_h_kernel(
    const float* __restrict__ X, const float* __restrict__ scale,
    __bf16* __restrict__ Ah, __bf16* __restrict__ Al)
{
  int tid = blockIdx.x * 256 + threadIdx.x;   // RTILES*16*16
  int row = tid >> 4, kc = tid & 15;
  float v[8];
  if (row < NN) {
    const float4* p = (const float4*)(X + row * 128 + kc * 8);
    float4 a = p[0], b = p[1];
    float s = scale ? scale[row] : 1.f;
    v[0] = a.x * s; v[1] = a.y * s; v[2] = a.z * s; v[3] = a.w * s;
    v[4] = b.x * s; v[5] = b.y * s; v[6] = b.z * s; v[7] = b.w * s;
  } else {
#pragma unroll
    for (int i = 0; i < 8; ++i) v[i] = 0.f;
  }
  bf16x8 hi, lo;
#pragma unroll
  for (int i = 0; i < 8; ++i) {
    __bf16 h = (__bf16)v[i];
    hi[i] = h;
    lo[i] = (__bf16)(v[i] - (float)h);
  }
  int off = frag_off(row, kc);
  *(bf16x8*)(Ah + off) = hi;
  *(bf16x8*)(Al + off) = lo;
}

// ---------------- bf16x3 MFMA GEMM (bf16 output) ----------------
__global__ __launch_bounds__(256) void gemm_mfma(
    const __bf16* __restrict__ Ah, const __bf16* __restrict__ Al,
    const __bf16* __restrict__ Wmat, const float* __restrict__ bias,
    __bf16* __restrict__ outb)
{
  __shared__ __bf16 wt[8192];
  int tid = threadIdx.x;
  int wid = tid >> 6, lane = tid & 63;
  int wr = wid >> 1, wc = wid & 1;
  int l15 = lane & 15, l4 = lane >> 4;
  f32x4 acc[4][4];
#pragma unroll
  for (int a = 0; a < 4; ++a)
#pragma unroll
    for (int b = 0; b < 4; ++b) acc[a][b] = (f32x4){0.f, 0.f, 0.f, 0.f};
  int rowtile0 = blockIdx.x * 8 + wr * 4;

  for (int ks = 0; ks < 4; ++ks) {
    {
      const bf16x8* g = (const bf16x8*)(Wmat + ks * 8192);
      bf16x8* l = (bf16x8*)wt;
      l[tid]       = g[tid];
      l[tid + 256] = g[tid + 256];
      l[tid + 512] = g[tid + 512];
      l[tid + 768] = g[tid + 768];
    }
    bf16x8 ah[4], al[4];
#pragma unroll
    for (int rt = 0; rt < 4; ++rt) {
      int off = (rowtile0 + rt) * 2048 + ks * 512 + lane * 8;
      ah[rt] = *(const bf16x8*)(Ah + off);
      al[rt] = *(const bf16x8*)(Al + off);
    }
    __syncthreads();
#pragma unroll
    for (int ct = 0; ct < 4; ++ct) {
      int n = wc * 64 + ct * 16 + l15;
      int ei = (n * 32 + l4 * 8) ^ ((n & 7) << 3);
      bf16x8 bh = *(const bf16x8*)(wt + ei);
      bf16x8 bl = *(const bf16x8*)(wt + 4096 + ei);
#pragma unroll
      for (int rt = 0; rt < 4; ++rt) {
        acc[rt][ct] = __builtin_amdgcn_mfma_f32_16x16x32_bf16(ah[rt], bh, acc[rt][ct], 0, 0, 0);
        acc[rt][ct] = __builtin_amdgcn_mfma_f32_16x16x32_bf16(ah[rt], bl, acc[rt][ct], 0, 0, 0);
        acc[rt][ct] = __builtin_amdgcn_mfma_f32_16x16x32_bf16(al[rt], bh, acc[rt][ct], 0, 0, 0);
      }
    }
    __syncthreads();
  }
  int rowbase = blockIdx.x * 128 + wr * 64;
#pragma unroll
  for (int ct = 0; ct < 4; ++ct) {
    int col = wc * 64 + ct * 16 + l15;
    float b = bias ? bias[col] : 0.f;
#pragma unroll
    for (int rt = 0; rt < 4; ++rt) {
#pragma unroll
      for (int r = 0; r < 4; ++r) {
        int row = rowbase + rt * 16 + l4 * 4 + r;
        if (row < NN) outb[row * 128 + col] = (__bf16)(acc[rt][ct][r] + b);
      }
    }
  }
}

// ---------------- GraphConv aggregation: bf16 gather, 64 thr/node, x4 unroll ----------------
__global__ __launch_bounds__(64) void gc_agg_kernel(
    const __bf16* __restrict__ mb, const int* __restrict__ rowoff,
    const int* __restrict__ indeg, const int* __restrict__ csr_src,
    const float2* __restrict__ bias2, const float* __restrict__ nsrow,
    float2* __restrict__ out2,        // null = skip fp32 write
    __bf16* __restrict__ Ah, __bf16* __restrict__ Al)   // null = skip split
{
  __shared__ float buf[128];
  int d = blockIdx.x, c = threadIdx.x;
  int ro = rowoff[d], dg = indeg[d];
  float2 a0 = {0.f, 0.f}, a1 = {0.f, 0.f}, a2 = {0.f, 0.f}, a3 = {0.f, 0.f};
  int j = 0;
  for (; j + 4 <= dg; j += 4) {
    int s0 = csr_src[ro + j], s1 = csr_src[ro + j + 1];
    int s2 = csr_src[ro + j + 2], s3 = csr_src[ro + j + 3];
    float2 v0 = unpk2(*(const unsigned*)(mb + s0 * 128 + 2 * c));
    float2 v1 = unpk2(*(const unsigned*)(mb + s1 * 128 + 2 * c));
    float2 v2 = unpk2(*(const unsigned*)(mb + s2 * 128 + 2 * c));
    float2 v3 = unpk2(*(const unsigned*)(mb + s3 * 128 + 2 * c));
    a0.x += v0.x; a0.y += v0.y; a1.x += v1.x; a1.y += v1.y;
    a2.x += v2.x; a2.y += v2.y; a3.x += v3.x; a3.y += v3.y;
  }
  for (; j < dg; ++j) {
    float2 v = unpk2(*(const unsigned*)(mb + csr_src[ro + j] * 128 + 2 * c));
    a0.x += v.x; a0.y += v.y;
  }
  float accx = (a0.x + a1.x) + (a2.x + a3.x);
  float accy = (a0.y + a1.y) + (a2.y + a3.y);
  float ndv = rsqrtf((float)max(dg, 1));
  float2 b = bias2[c];
  float vx = fmaxf(accx * ndv + b.x, 0.f);
  float vy = fmaxf(accy * ndv + b.y, 0.f);
  if (out2) out2[d * 64 + c] = make_float2(vx, vy);
  if (Ah) {
    float s = nsrow ? nsrow[d] : 1.f;
    ((float2*)buf)[c] = make_float2(vx * s, vy * s);
    __syncthreads();
    if (c < 32) {
      int kc = c & 15;
      int off = frag_off(d, kc);
      bf16x8 pk;
      if (c < 16) {
#pragma unroll
        for (int i = 0; i < 8; ++i) pk[i] = (__bf16)buf[kc * 8 + i];
        *(bf16x8*)(Ah + off) = pk;
      } else {
#pragma unroll
        for (int i = 0; i < 8; ++i) {
          float x = buf[kc * 8 + i];
          __bf16 hh = (__bf16)x;
          pk[i] = (__bf16)(x - (float)hh);
        }
        *(bf16x8*)(Al + off) = pk;
      }
    }
  }
}

// ---------------- Fused GATv2: bf16 fs gather + bf16 fd, DPP reduce, online softmax ----------------
__global__ __launch_bounds__(64) void gat_node_kernel(
    const __bf16* __restrict__ fsb,   // [N][128] bf16
    const __bf16* __restrict__ fdb,   // [N][128] bf16
    const float* __restrict__ attn,
    const int* __restrict__ rowoff, const int* __restrict__ indeg,
    const int* __restrict__ csr_src,
    float2* __restrict__ h2,          // in/out
    __bf16* __restrict__ Ah, __bf16* __restrict__ Al)   // null = skip split
{
  __shared__ float buf[128];
  int d = blockIdx.x, c = threadIdx.x;
  int ro = rowoff[d], dg = indeg[d];
  float2 fdp = unpk2(*(const unsigned*)(fdb + d * 128 + 2 * c));
  float2 ap = ((const float2*)attn)[c];
  float mA = -INFINITY, sA = 0.f; float2 aA = {0.f, 0.f};
  float mB = -INFINITY, sB = 0.f; float2 aB = {0.f, 0.f};
  int j = 0;
  for (; j + 2 <= dg; j += 2) {
    int s0 = csr_src[ro + j], s1 = csr_src[ro + j + 1];
    float2 f0 = unpk2(*(const unsigned*)(fsb + s0 * 128 + 2 * c));
    float2 f1 = unpk2(*(const unsigned*)(fsb + s1 * 128 + 2 * c));
    float x0 = f0.x + fdp.x; x0 = fmaxf(x0, 0.f) + 0.2f * fminf(x0, 0.f);
    float z0 = f0.y + fdp.y; z0 = fmaxf(z0, 0.f) + 0.2f * fminf(z0, 0.f);
    float x1 = f1.x + fdp.x; x1 = fmaxf(x1, 0.f) + 0.2f * fminf(x1, 0.f);
    float z1 = f1.y + fdp.y; z1 = fmaxf(z1, 0.f) + 0.2f * fminf(z1, 0.f);
    float y0 = rowsum8(ap.x * x0 + ap.y * z0);
    float y1 = rowsum8(ap.x * x1 + ap.y * z1);
    float nm = fmaxf(mA, y0);
    float sc = __expf(mA - nm), p = __expf(y0 - nm);
    sA = sA * sc + p; aA.x = aA.x * sc + p * f0.x; aA.y = aA.y * sc + p * f0.y; mA = nm;
    nm = fmaxf(mB, y1);
    sc = __expf(mB - nm); p = __expf(y1 - nm);
    sB = sB * sc + p; aB.x = aB.x * sc + p * f1.x; aB.y = aB.y * sc + p * f1.y; mB = nm;
  }
  if (j < dg) {
    int s0 = csr_src[ro + j];
    float2 f0 = unpk2(*(const unsigned*)(fsb + s0 * 128 + 2 * c));
    float x0 = f0.x + fdp.x; x0 = fmaxf(x0, 0.f) + 0.2f * fminf(x0, 0.f);
    float z0 = f0.y + fdp.y; z0 = fmaxf(z0, 0.f) + 0.2f * fminf(z0, 0.f);
    float y0 = rowsum8(ap.x * x0 + ap.y * z0);
    float nm = fmaxf(mA, y0);
    float sc = __expf(mA - nm), p = __expf(y0 - nm);
    sA = sA * sc + p; aA.x = aA.x * sc + p * f0.x; aA.y = aA.y * sc + p * f0.y; mA = nm;
  }
  float ox = 0.f, oy = 0.f;
  if (dg > 0) {
    float M = fmaxf(mA, mB);
    float eA = __expf(mA - M), eB = __expf(mB - M);   // exp(-inf)=0 handles dg==1
    float inv = 1.f / (sA * eA + sB * eB);
    ox = (aA.x * eA + aB.x * eB) * inv;
    oy = (aA.y * eA + aB.y * eB) * inv;
  }
  float2 hv = h2[d * 64 + c];
  float vx = fmaxf(ox + hv.x, 0.f);
  float vy = fmaxf(oy + hv.y, 0.f);
  h2[d * 64 + c] = make_float2(vx, vy);
  if (Ah) {
    ((float2*)buf)[c] = make_float2(vx, vy);
    __syncthreads();
    if (c < 32) {
      int kc = c & 15;
      int off = frag_off(d, kc);
      bf16x8 pk;
      if (c < 16) {
#pragma unroll
        for (int i = 0; i < 8; ++i) pk[i] = (__bf16)buf[kc * 8 + i];
        *(bf16x8*)(Ah + off) = pk;
      } else {
#pragma unroll
        for (int i = 0; i < 8; ++i) {
          float x = buf[kc * 8 + i];
          __bf16 hh = (__bf16)x;
          pk[i] = (__bf16)(x - (float)hh);
        }
        *(bf16x8*)(Al + off) = pk;
      }
    }
  }
}

// ---------------- pooling (n2g sorted: per-graph range + few atomics) ----------------
__global__ __launch_bounds__(128) void pool_kernel(const float* __restrict__ h,
                                                   const int* __restrict__ n2g,
                                                   unsigned* __restrict__ hg)
{
  int g = blockIdx.x >> 3, chunk = blockIdx.x & 7, c = threadIdx.x;
  int lo = 0, hi = NN;
  while (lo < hi) { int mid = (lo + hi) >> 1; if (n2g[mid] < g) lo = mid + 1; else hi = mid; }
  int start = lo;
  hi = NN;
  while (lo < hi) { int mid = (lo + hi) >> 1; if (n2g[mid] < g + 1) lo = mid + 1; else hi = mid; }
  int end = lo;
  int len = end - start;
  int s = start + (int)(((long long)len * chunk) >> 3);
  int e = start + (int)(((long long)len * (chunk + 1)) >> 3);
  float m = 0.f;
  for (int r = s; r < e; ++r) m = fmaxf(m, h[r * 128 + c]);
  atomicMax(&hg[g * 128 + c], __float_as_uint(m));
}

__global__ __launch_bounds__(128) void mlp_kernel(
    const float* __restrict__ hg,
    const float* __restrict__ Wc1, const float* __restrict__ bc1,
    const float* __restrict__ Wc2, const float* __restrict__ bc2,
    const float* __restrict__ Wc3, const float* __restrict__ bc3,
    float* __restrict__ out)
{
  __shared__ float x[128], z1[128], z2[64];
  int g = blockIdx.x, t = threadIdx.x;
  x[t] = hg[g * 128 + t];
  __syncthreads();
  float acc = bc1[t];
  for (int k = 0; k < 128; ++k) acc += x[k] * Wc1[k * 128 + t];
  z1[t] = fmaxf(acc, 0.f);
  __syncthreads();
  if (t < 64) {
    float a2 = bc2[t];
    for (int k = 0; k < 128; ++k) a2 += z1[k] * Wc2[k * 64 + t];
    z2[t] = fmaxf(a2, 0.f);
  }
  __syncthreads();
#pragma unroll
  for (int p = 0; p < 2; ++p) {
    int c = t + p * 128;
    float a3 = bc3[c];
    for (int k = 0; k < 64; ++k) a3 += z2[k] * Wc3[k * 256 + c];
    out[g * 256 + c] = a3;
  }
}

// ---------------- launch ----------------
extern "C" void kernel_launch(void* const* d_in, const int* in_sizes, int n_in,
                              void* d_out, int out_size, void* d_ws, size_t ws_size,
                              hipStream_t stream)
{
  const float* feature = (const float*)d_in[0];
  const float* W_gc1 = (const float*)d_in[1];
  const float* b_gc1 = (const float*)d_in[2];
  const float* W_gc2 = (const float*)d_in[3];
  const float* b_gc2 = (const float*)d_in[4];
  const float* W_src = (const float*)d_in[5];
  const float* b_src = (const float*)d_in[6];
  const float* W_dst = (const float*)d_in[7];
  const float* b_dst = (const float*)d_in[8];
  const float* attn  = (const float*)d_in[9];
  const float* Wc1 = (const float*)d_in[10];
  const float* bc1 = (const float*)d_in[11];
  const float* Wc2 = (const float*)d_in[12];
  const float* bc2 = (const float*)d_in[13];
  const float* Wc3 = (const float*)d_in[14];
  const float* bc3 = (const float*)d_in[15];
  const int* src = (const int*)d_in[16];
  const int* dst = (const int*)d_in[17];
  const int* n2g = (const int*)d_in[18];

  char* base = (char*)d_ws;
  int* indeg  = (int*)base;            base += NN * sizeof(int);
  int* outdeg = (int*)base;            base += NN * sizeof(int);
  int* rowoff = (int*)base;            base += NN * sizeof(int);
  int* cursor = (int*)base;            base += NN * sizeof(int);
  int* bsum   = (int*)base;            base += 256 * sizeof(int);
  int* csr_src = (int*)base;           base += EE * sizeof(int);
  float* ns = (float*)base;            base += NN * sizeof(float);
  float* h0 = (float*)base;            base += (size_t)NN * HIDD * sizeof(float);
  __bf16* fsb = (__bf16*)base;         base += (size_t)NN * HIDD * sizeof(__bf16);
  __bf16* fdb = (__bf16*)base;         base += (size_t)NN * HIDD * sizeof(__bf16);
  __bf16* mb  = (__bf16*)base;         base += (size_t)NN * HIDD * sizeof(__bf16);
  __bf16* Ah = (__bf16*)base;          base += (size_t)RTILES * 2048 * sizeof(__bf16);
  __bf16* Al = (__bf16*)base;          base += (size_t)RTILES * 2048 * sizeof(__bf16);
  __bf16* Wblk = (__bf16*)base;        base += (size_t)8 * 32768 * sizeof(__bf16);
  float* hg = (float*)base;            base += GG * HIDD * sizeof(float);

  // degrees, norms, CSR
  hipMemsetAsync(indeg, 0, 2 * NN * sizeof(int), stream);
  deg_kernel<<<2048, 256, 0, stream>>>(src, dst, outdeg, indeg);
  norm_kernel<<<NBLK, 256, 0, stream>>>(outdeg, ns);
  scan1_kernel<<<NBLK, 256, 0, stream>>>(indeg, rowoff, bsum);
  scan2_kernel<<<1, 256, 0, stream>>>(bsum);
  scan3_kernel<<<NBLK, 256, 0, stream>>>(rowoff, bsum, cursor);
  bin_kernel<<<2048, 256, 0, stream>>>(src, dst, cursor, csr_src);

  // weight split (all 8 matrices)
  split_w_kernel<<<512, 256, 0, stream>>>(W_gc1, W_gc2, W_src, W_dst, Wblk);

  const int split_grid = RTILES * 16 * 16 / 256;

  // GC1: split(feature*ns) -> gemm (bf16 m) -> agg (writes next split, scaled by ns)
  split_h_kernel<<<split_grid, 256, 0, stream>>>(feature, ns, Ah, Al);
  gemm_mfma<<<GEMM_GRID, 256, 0, stream>>>(Ah, Al, Wblk + 0 * 32768, nullptr, mb);
  gc_agg_kernel<<<NN, 64, 0, stream>>>(mb, rowoff, indeg, csr_src,
                                       (const float2*)b_gc1, ns, nullptr, Ah, Al);
  // GC2: gemm (bf16 m) -> agg (writes h0 + unscaled split for GAT1)
  gemm_mfma<<<GEMM_GRID, 256, 0, stream>>>(Ah, Al, Wblk + 1 * 32768, nullptr, mb);
  gc_agg_kernel<<<NN, 64, 0, stream>>>(mb, rowoff, indeg, csr_src,
                                       (const float2*)b_gc2, nullptr, (float2*)h0, Ah, Al);

  // GATv2 x3: fs and fd both bf16
  for (int i = 0; i < 3; ++i) {
    gemm_mfma<<<GEMM_GRID, 256, 0, stream>>>(Ah, Al, Wblk + (2 + i) * 32768, b_src + i * HIDD, fsb);
    gemm_mfma<<<GEMM_GRID, 256, 0, stream>>>(Ah, Al, Wblk + (5 + i) * 32768, b_dst + i * HIDD, fdb);
    bool last = (i == 2);
    gat_node_kernel<<<NN, 64, 0, stream>>>(fsb, fdb,
                                           attn + i * HEADS * DHH,
                                           rowoff, indeg, csr_src, (float2*)h0,
                                           last ? nullptr : Ah, last ? nullptr : Al);
  }

  // pooling + MLP
  hipMemsetAsync(hg, 0, GG * HIDD * sizeof(float), stream);
  pool_kernel<<<GG * 8, 128, 0, stream>>>(h0, n2g, (unsigned*)hg);
  mlp_kernel<<<GG, 128, 0, stream>>>(hg, Wc1, bc1, Wc2, bc2, Wc3, bc3, (float*)d_out);
}